// Round 8
// baseline (260.147 us; speedup 1.0000x reference)
//
#include <hip/hip_runtime.h>
#include <hip/hip_bf16.h>

// FactorizedDotProductAttention on MI355X (gfx950)
// B=8, N=3136 (=T16 * P196), C=768, H=12, hd=64. Heads 0-5: spatial attn over P=196
// per (b,t). Heads 6-11: temporal attn over T=16 per (b,p).
// Pipeline: prep ; QKV GEMM (256^2 8-phase) ; fused attn (swapped-QK^T, lane-local P,
// permuted-V LDS, no P LDS) ; out GEMM (128^2 2-phase dbuf).

typedef __attribute__((ext_vector_type(8))) short short8;
typedef __attribute__((ext_vector_type(4))) float f32x4;
typedef __attribute__((ext_vector_type(4))) unsigned int u32x4;

typedef __attribute__((address_space(1))) void gvoid;
typedef __attribute__((address_space(3))) void lvoid;

__device__ __forceinline__ unsigned short f2b(float f) {
  unsigned int u = __float_as_uint(f);
  unsigned int r = (u + 0x7FFFu + ((u >> 16) & 1u)) >> 16;  // RNE
  return (unsigned short)r;
}

__device__ __forceinline__ unsigned int pk2(float a, float b) {  // 2xbf16 packed (RNE)
  union { __hip_bfloat162 h; unsigned int u; } cv;
  cv.h = __float22bfloat162_rn(float2{a, b});
  return cv.u;
}

// permuted V column within a 32-key group: slot->key map of the 16x16x32 A-frag
// (key bits k4k3k2k1k0 -> col k3<<4 | k2<<3 | k4<<2 | k1<<1 | k0)
__device__ __forceinline__ int vperm(int key) {
  int u = key & 31;
  return (key & ~31) | (((u >> 3) & 1) << 4) | (((u >> 2) & 1) << 3) |
         (((u >> 4) & 1) << 2) | (u & 3);
}

// ---------- kernel 1: prep = convert x (blocks 0..18815) + pack W (blocks 18816..21119) ----------
__global__ __launch_bounds__(256) void k_prep(
    const float* __restrict__ x, unsigned short* __restrict__ xb,
    const float* __restrict__ bq, const float* __restrict__ bk,
    const float* __restrict__ bv, float* __restrict__ bqkv,
    const float* __restrict__ Wq, const float* __restrict__ Wk,
    const float* __restrict__ Wv, const float* __restrict__ Wo,
    unsigned short* __restrict__ wqkvT, unsigned short* __restrict__ woT) {
  __shared__ float tile[32][33];
  if (blockIdx.x < 18816) {
    int tid = blockIdx.x * 256 + threadIdx.x;
    if (tid < 2304)
      bqkv[tid] = tid < 768 ? bq[tid] : (tid < 1536 ? bk[tid - 768] : bv[tid - 1536]);
    float4 v = ((const float4*)x)[tid];
    ushort4 o;
    o.x = f2b(v.x); o.y = f2b(v.y); o.z = f2b(v.z); o.w = f2b(v.w);
    ((ushort4*)xb)[tid] = o;
    return;
  }
  int bid = blockIdx.x - 18816;
  const float* W;
  unsigned short* dst;
  int n0, k0;
  if (bid < 1728) {
    int tn = bid % 72, tk = bid / 72;
    n0 = tn * 32; k0 = tk * 32;
    int which = n0 / 768;
    W = which == 0 ? Wq : (which == 1 ? Wk : Wv);
    dst = wqkvT;
  } else {
    int b2 = bid - 1728;
    int tn = b2 % 24, tk = b2 / 24;
    n0 = tn * 32; k0 = tk * 32;
    W = Wo; dst = woT;
  }
  int nn0 = n0 % 768;
  for (int i = threadIdx.x; i < 1024; i += 256) {
    int r = i >> 5, c = i & 31;
    tile[r][c] = W[(size_t)(k0 + r) * 768 + nn0 + c];
  }
  __syncthreads();
  for (int i = threadIdx.x; i < 1024; i += 256) {
    int r = i >> 5, c = i & 31;
    dst[(size_t)(n0 + r) * 768 + k0 + c] = f2b(tile[c][r]);
  }
}

// ================== 256x256 8-phase GEMM, K=768, 1 barrier/phase ==================
// Round-4 proven schedule. See prior rounds for the WAR/RAW audit.

#define FENCE asm volatile("" ::: "memory")
#define BARRIER do { FENCE; __builtin_amdgcn_s_barrier(); FENCE; } while (0)
#define WAIT_LGKM0 asm volatile("s_waitcnt lgkmcnt(0)" ::: "memory")
#define WAIT_VM4 asm volatile("s_waitcnt vmcnt(4)" ::: "memory")

#define STAGE(PBASE, BUFBASE, HT, KT_) do {                                          \
    int kt__ = (KT_);                                                                \
    bool real__ = (kt__ < 12);                                                       \
    if (!real__) kt__ -= 12;                                                         \
    const unsigned short* src__ = (PBASE) + (HT) * 98304 + kt__ * 64;                \
    unsigned d0__ = real__ ? ((BUFBASE) + (HT) * 8192 + w * 512) : (65536u + w * 512); \
    unsigned d1__ = real__ ? ((BUFBASE) + (HT) * 8192 + 4096 + w * 512) : (65536u + w * 512); \
    __builtin_amdgcn_global_load_lds((const gvoid*)src__, (lvoid*)(lds + d0__), 16, 0, 0); \
    __builtin_amdgcn_global_load_lds((const gvoid*)(src__ + 49152), (lvoid*)(lds + d1__), 16, 0, 0); \
  } while (0)

#define LDA(MH, ABASE) do {                                                          \
    const unsigned short* ab__ = lds + (ABASE) + ((MH) * 128 + arow) * 64;           \
    _Pragma("unroll")                                                                \
    for (int mf = 0; mf < 4; ++mf) {                                                 \
      af[mf][0] = *(const short8*)(ab__ + mf * 1024 + s0);                           \
      af[mf][1] = *(const short8*)(ab__ + mf * 1024 + s1);                           \
    }                                                                                \
  } while (0)

#define LDB(NH, BBASE) do {                                                          \
    const unsigned short* bb__ = lds + (BBASE) + ((NH) * 128 + brow) * 64;           \
    _Pragma("unroll")                                                                \
    for (int nf = 0; nf < 2; ++nf) {                                                 \
      bf[nf][0] = *(const short8*)(bb__ + nf * 1024 + s0);                           \
      bf[nf][1] = *(const short8*)(bb__ + nf * 1024 + s1);                           \
    }                                                                                \
  } while (0)

#define MM(MH, NH) do {                                                              \
    __builtin_amdgcn_s_setprio(1);                                                   \
    _Pragma("unroll")                                                                \
    for (int mf = 0; mf < 4; ++mf) {                                                 \
      _Pragma("unroll")                                                              \
      for (int nf = 0; nf < 2; ++nf) {                                               \
        acc[MH][mf][NH][nf] = __builtin_amdgcn_mfma_f32_16x16x32_bf16(               \
            af[mf][0], bf[nf][0], acc[MH][mf][NH][nf], 0, 0, 0);                     \
        acc[MH][mf][NH][nf] = __builtin_amdgcn_mfma_f32_16x16x32_bf16(               \
            af[mf][1], bf[nf][1], acc[MH][mf][NH][nf], 0, 0, 0);                     \
      }                                                                              \
    }                                                                                \
    __builtin_amdgcn_s_setprio(0);                                                   \
  } while (0)

__global__ __launch_bounds__(512, 2) void k_gemm256(
    const unsigned short* __restrict__ A, const unsigned short* __restrict__ Bt,
    const float* __restrict__ bias, unsigned short* __restrict__ Cout,
    int M, int N) {
  __shared__ __align__(16) unsigned short lds[69632];
  const int nwg = gridDim.x;
  const int nbx = N >> 8;
  const int orig = blockIdx.x;
  const int q = nwg >> 3, r = nwg & 7;
  const int xcd = orig & 7, lin = orig >> 3;
  const int wg = (xcd < r ? xcd * (q + 1) : r * (q + 1) + (xcd - r) * q) + lin;
  const int m0 = (wg / nbx) << 8, n0 = (wg % nbx) << 8;

  const int tid = threadIdx.x;
  const int w = tid >> 6, l = tid & 63;
  const int wm = w >> 2, wn = w & 3;
  const int lg = l >> 4, ln = l & 15;
  const int arow = wm * 64 + ln;
  const int brow = wn * 32 + ln;
  const int s0 = (lg ^ (ln & 7)) * 8;
  const int s1 = s0 ^ 32;
  const int srow = tid >> 3;
  const int slg8 = ((tid & 7) ^ (srow & 7)) * 8;
  const unsigned short* pA = A + (size_t)(m0 + srow) * 768 + slg8;
  const unsigned short* pB = Bt + (size_t)(n0 + srow) * 768 + slg8;

  f32x4 acc[2][4][2][2] = {};

  STAGE(pA, 0,     0, 0);
  STAGE(pB, 16384, 0, 0);
  STAGE(pA, 0,     1, 0);
  STAGE(pB, 16384, 1, 0);
  STAGE(pA, 32768, 0, 1);
  STAGE(pB, 49152, 1, 1);
  WAIT_VM4;
  BARRIER;

  for (int it = 0; it < 6; ++it) {
    const int kt1 = 2 * it + 1, ktn0 = 2 * it + 2, ktn1 = 2 * it + 3;
    short8 af[4][2], bf[2][2];
    LDA(0, 0); LDB(0, 16384);
    STAGE(pA, 32768, 1, kt1);
    BARRIER; WAIT_LGKM0; MM(0, 0);
    LDB(1, 16384);
    STAGE(pB, 49152, 0, kt1);
    BARRIER; WAIT_LGKM0; MM(0, 1);
    LDA(1, 0);
    STAGE(pA, 0, 0, ktn0);
    BARRIER; WAIT_LGKM0; MM(1, 1);
    LDB(0, 16384);
    STAGE(pB, 16384, 1, ktn0);
    WAIT_VM4;
    BARRIER; WAIT_LGKM0; MM(1, 0);
    LDA(0, 32768); LDB(0, 49152);
    STAGE(pA, 0, 1, ktn0);
    BARRIER; WAIT_LGKM0; MM(0, 0);
    LDB(1, 49152);
    STAGE(pB, 16384, 0, ktn0);
    BARRIER; WAIT_LGKM0; MM(0, 1);
    LDA(1, 32768);
    STAGE(pA, 32768, 0, ktn1);
    BARRIER; WAIT_LGKM0; MM(1, 1);
    LDB(0, 49152);
    STAGE(pB, 49152, 1, ktn1);
    WAIT_VM4;
    BARRIER; WAIT_LGKM0; MM(1, 0);
  }

#pragma unroll
  for (int mh = 0; mh < 2; ++mh)
#pragma unroll
    for (int mf = 0; mf < 4; ++mf)
#pragma unroll
      for (int nh = 0; nh < 2; ++nh)
#pragma unroll
        for (int nf = 0; nf < 2; ++nf) {
          const int col = n0 + nh * 128 + wn * 32 + nf * 16 + ln;
          const float bval = bias[col];
          const int row = m0 + mh * 128 + wm * 64 + mf * 16 + lg * 4;
#pragma unroll
          for (int rr = 0; rr < 4; ++rr)
            Cout[(size_t)(row + rr) * N + col] = f2b(acc[mh][mf][nh][nf][rr] + bval);
        }
}

// ---------- out GEMM: 128x128, BK=32, double-buffered 2-phase ----------
__global__ __launch_bounds__(256) void k_gemm_out(
    const unsigned short* __restrict__ A, const unsigned short* __restrict__ Bt,
    const float* __restrict__ bias, float* __restrict__ C,
    int M, int N, int K) {
  __shared__ __align__(16) unsigned short As[2][128 * 32];
  __shared__ __align__(16) unsigned short Bs[2][128 * 32];
  const int tid = threadIdx.x;
  const int w = tid >> 6, l = tid & 63;
  const int lg = l >> 4, ln = l & 15;
  const int m0 = blockIdx.y * 128, n0 = blockIdx.x * 128;
  const int wr = (w >> 1) * 64, wc = (w & 1) * 64;
  f32x4 acc[4][4] = {};
  const unsigned short* ga = A + (size_t)(m0 + (tid >> 2)) * K + ((tid & 3) * 8);
  const unsigned short* gb = Bt + (size_t)(n0 + (tid >> 2)) * K + ((tid & 3) * 8);
  const size_t krow64 = (size_t)64 * K;
  const int wofs = w * 512;

#define OSTAGE(CO, K0) do {                                                                        \
    __builtin_amdgcn_global_load_lds((const gvoid*)(ga + (K0)),          (lvoid*)(&As[0][0] + (CO) + wofs),        16, 0, 0); \
    __builtin_amdgcn_global_load_lds((const gvoid*)(ga + krow64 + (K0)), (lvoid*)(&As[0][0] + (CO) + 2048 + wofs), 16, 0, 0); \
    __builtin_amdgcn_global_load_lds((const gvoid*)(gb + (K0)),          (lvoid*)(&Bs[0][0] + (CO) + wofs),        16, 0, 0); \
    __builtin_amdgcn_global_load_lds((const gvoid*)(gb + krow64 + (K0)), (lvoid*)(&Bs[0][0] + (CO) + 2048 + wofs), 16, 0, 0); \
  } while (0)

  OSTAGE(0, 0);
  asm volatile("s_waitcnt vmcnt(0)" ::: "memory");
  BARRIER;
  int co = 0;
  for (int k0 = 0; k0 < K; k0 += 32) {
    if (k0 + 32 < K) OSTAGE(co ^ 4096, k0 + 32);
    const unsigned short* as = &As[0][0] + co;
    const unsigned short* bs = &Bs[0][0] + co;
    short8 a[4], b[4];
#pragma unroll
    for (int mt = 0; mt < 4; ++mt)
      a[mt] = *(const short8*)(as + (wr + mt * 16 + ln) * 32 + lg * 8);
#pragma unroll
    for (int nt = 0; nt < 4; ++nt)
      b[nt] = *(const short8*)(bs + (wc + nt * 16 + ln) * 32 + lg * 8);
#pragma unroll
    for (int mt = 0; mt < 4; ++mt)
#pragma unroll
      for (int nt = 0; nt < 4; ++nt)
        acc[mt][nt] = __builtin_amdgcn_mfma_f32_16x16x32_bf16(a[mt], b[nt], acc[mt][nt], 0, 0, 0);
    asm volatile("s_waitcnt vmcnt(0)" ::: "memory");
    BARRIER;
    co ^= 4096;
  }
#pragma unroll
  for (int nt = 0; nt < 4; ++nt) {
    int col = n0 + wc + nt * 16 + ln;
    float bval = bias[col];
#pragma unroll
    for (int mt = 0; mt < 4; ++mt) {
      int row = m0 + wr + mt * 16 + lg * 4;
#pragma unroll
      for (int r = 0; r < 4; ++r)
        C[(size_t)(row + r) * N + col] = acc[mt][nt][r] + bval;
    }
  }
#undef OSTAGE
}

// ---------- fused attention (swapped QK^T, lane-local P, permuted V) ----------
// Spatial (blocks 0..767, one per (b,t,h)): s = mfma(K,Q) -> lane (ln,lg) holds
// S[key=nt*16+lg*4+r][q=mt*16+ln]. Softmax over keys: local sum + shfl_xor(16,32).
// P stays in registers: 16x16x32 PV A-frag slot (lg,j) needs key
// (2ks+(j>=4))*16+lg*4+(j&3) = exactly st[2ks+(j>=4)][j&3]. V^T staged with the
// matching column bit-permutation so the B-frag read is a plain short8.
// 1/sum folded into the store via shfl(inv, lg*4+r). No max-subtract (|s|<~4).
// Temporal (blocks 768..3119, one wave per (b,p,h)): same with one 16-key tile.
__global__ __launch_bounds__(256) void k_attn_fused(
    const unsigned short* __restrict__ qkv, unsigned short* __restrict__ attn) {
  __shared__ __align__(16) unsigned short smem[14848];  // 29696 B
  const int w = threadIdx.x >> 6, l = threadIdx.x & 63;
  const int lg = l >> 4, ln = l & 15;
  const float scale = 0.125f;
  if (blockIdx.x < 768) {
    // ---- spatial: heads 0-5 ----
    const int bi = blockIdx.x;
    const int h = bi % 6;
    const int t = (bi / 6) % 16;
    const int b = bi / 96;
    const int base_row = b * 3136 + t * 196;
    unsigned short* Vt = smem;  // [64][232], permuted cols
    for (int i = threadIdx.x; i < 196 * 8; i += 256) {
      int key = i >> 3, d0 = (i & 7) * 8;
      short8 v = *(const short8*)(qkv + (size_t)(base_row + key) * 2304 + 1536 + h * 64 + d0);
      int col = vperm(key);
#pragma unroll
      for (int j = 0; j < 8; ++j) Vt[(d0 + j) * 232 + col] = (unsigned short)v[j];
    }
    for (int i = threadIdx.x; i < 64 * 28; i += 256)
      Vt[(i / 28) * 232 + 196 + (i % 28)] = 0;  // keys 196..223 land in cols 196..223
    __syncthreads();
    for (int mt = w; mt < 13; mt += 4) {
      int qm = mt * 16 + ln; if (qm > 195) qm = 195;
      const size_t qoff = (size_t)(base_row + qm) * 2304 + h * 64 + lg * 8;
      short8 qb0 = *(const short8*)(qkv + qoff);
      short8 qb1 = *(const short8*)(qkv + qoff + 32);
      f32x4 st[13];
#pragma unroll
      for (int nt = 0; nt < 13; ++nt) {
        int kn = nt * 16 + ln; if (kn > 195) kn = 195;
        const size_t koff = (size_t)(base_row + kn) * 2304 + 768 + h * 64 + lg * 8;
        short8 ka0 = *(const short8*)(qkv + koff);
        short8 ka1 = *(const short8*)(qkv + koff + 32);
        f32x4 s = {0.f, 0.f, 0.f, 0.f};
        s = __builtin_amdgcn_mfma_f32_16x16x32_bf16(ka0, qb0, s, 0, 0, 0);  // swapped
        s = __builtin_amdgcn_mfma_f32_16x16x32_bf16(ka1, qb1, s, 0, 0, 0);
        st[nt] = s;
      }
      float sum = 0.f;
#pragma unroll
      for (int nt = 0; nt < 13; ++nt)
#pragma unroll
        for (int r = 0; r < 4; ++r) {
          bool valid = (nt * 16 + lg * 4 + r) < 196;
          float p = valid ? __expf(st[nt][r] * scale) : 0.f;
          st[nt][r] = p;
          sum += p;
        }
      sum += __shfl_xor(sum, 16);
      sum += __shfl_xor(sum, 32);
      float inv = 1.f / sum;
      float invR[4];
#pragma unroll
      for (int r = 0; r < 4; ++r) invR[r] = __shfl(inv, lg * 4 + r);  // inv of stored rows
      // pack P chunks (lane-local)
      short8 pa[7];
#pragma unroll
      for (int ks = 0; ks < 7; ++ks) {
        union { u32x4 u; short8 s; } pb;
        pb.u[0] = pk2(st[2 * ks][0], st[2 * ks][1]);
        pb.u[1] = pk2(st[2 * ks][2], st[2 * ks][3]);
        if (ks < 6) {
          pb.u[2] = pk2(st[2 * ks + 1][0], st[2 * ks + 1][1]);
          pb.u[3] = pk2(st[2 * ks + 1][2], st[2 * ks + 1][3]);
        } else {
          pb.u[2] = 0; pb.u[3] = 0;
        }
        pa[ks] = pb.s;
      }
#pragma unroll
      for (int nt4 = 0; nt4 < 4; ++nt4) {
        f32x4 acc = {0.f, 0.f, 0.f, 0.f};
#pragma unroll
        for (int ks = 0; ks < 7; ++ks) {
          short8 vb = *(const short8*)(Vt + (nt4 * 16 + ln) * 232 + ks * 32 + lg * 8);
          acc = __builtin_amdgcn_mfma_f32_16x16x32_bf16(pa[ks], vb, acc, 0, 0, 0);
        }
#pragma unroll
        for (int r = 0; r < 4; ++r) {
          int m = mt * 16 + lg * 4 + r;
          if (m < 196)
            attn[(size_t)(base_row + m) * 768 + h * 64 + nt4 * 16 + ln] = f2b(acc[r] * invR[r]);
        }
      }
    }
  } else {
    // ---- temporal: heads 6-11, one wave per (b,p,h) ----
    const int u = (blockIdx.x - 768) * 4 + w;  // 9408 = 8*196*6
    const int b = u / 1176;
    const int rem = u % 1176;
    const int p = rem / 6;
    const int h = 6 + rem % 6;
    const size_t rowb = (size_t)b * 3136 + p;
    unsigned short* Vt = smem + w * 2560;  // [64][40], permuted cols
    for (int i = l; i < 128; i += 64) {
      int tt = i >> 3, d0 = (i & 7) * 8;
      short8 v = *(const short8*)(qkv + (rowb + (size_t)tt * 196) * 2304 + 1536 + h * 64 + d0);
      int col = (((tt >> 3) & 1) << 4) | (((tt >> 2) & 1) << 3) | (tt & 3);
#pragma unroll
      for (int j = 0; j < 8; ++j) Vt[(d0 + j) * 40 + col] = (unsigned short)v[j];
    }
    for (int i = l; i < 1024; i += 64) {  // zero cols of keys 16..31 (bit2-set cols)
      int d = i >> 4, c = i & 15;
      Vt[d * 40 + (((c >> 2) << 3) + 4 + (c & 3))] = 0;
    }
    const size_t qoff = (rowb + (size_t)ln * 196) * 2304 + h * 64 + lg * 8;
    short8 qb0 = *(const short8*)(qkv + qoff);
    short8 qb1 = *(const short8*)(qkv + qoff + 32);
    short8 ka0 = *(const short8*)(qkv + qoff + 768);
    short8 ka1 = *(const short8*)(qkv + qoff + 768 + 32);
    f32x4 s = {0.f, 0.f, 0.f, 0.f};
    s = __builtin_amdgcn_mfma_f32_16x16x32_bf16(ka0, qb0, s, 0, 0, 0);  // swapped
    s = __builtin_amdgcn_mfma_f32_16x16x32_bf16(ka1, qb1, s, 0, 0, 0);
    float pv[4];
    float sum = 0.f;
#pragma unroll
    for (int r = 0; r < 4; ++r) { pv[r] = __expf(s[r] * scale); sum += pv[r]; }
    sum += __shfl_xor(sum, 16);
    sum += __shfl_xor(sum, 32);
    float inv = 1.f / sum;
    float invR[4];
#pragma unroll
    for (int r = 0; r < 4; ++r) invR[r] = __shfl(inv, lg * 4 + r);
    union { u32x4 u; short8 s; } pb;
    pb.u[0] = pk2(pv[0], pv[1]);
    pb.u[1] = pk2(pv[2], pv[3]);
    pb.u[2] = 0; pb.u[3] = 0;
#pragma unroll
    for (int nt4 = 0; nt4 < 4; ++nt4) {
      short8 vb = *(const short8*)(Vt + (nt4 * 16 + ln) * 40 + lg * 8);
      f32x4 acc = {0.f, 0.f, 0.f, 0.f};
      acc = __builtin_amdgcn_mfma_f32_16x16x32_bf16(pb.s, vb, acc, 0, 0, 0);
#pragma unroll
      for (int r = 0; r < 4; ++r) {
        int tq = lg * 4 + r;
        attn[((size_t)b * 3136 + (size_t)tq * 196 + p) * 768 + h * 64 + nt4 * 16 + ln] =
            f2b(acc[r] * invR[r]);
      }
    }
  }
}

// ---------- launch ----------
extern "C" void kernel_launch(void* const* d_in, const int* in_sizes, int n_in,
                              void* d_out, int out_size, void* d_ws, size_t ws_size,
                              hipStream_t stream) {
  const float* x  = (const float*)d_in[0];
  const float* Wq = (const float*)d_in[1];
  const float* bq = (const float*)d_in[2];
  const float* Wk = (const float*)d_in[3];
  const float* bk = (const float*)d_in[4];
  const float* Wv = (const float*)d_in[5];
  const float* bv = (const float*)d_in[6];
  const float* Wo = (const float*)d_in[7];
  const float* bo = (const float*)d_in[8];
  float* out = (float*)d_out;
  char* ws = (char*)d_ws;
  unsigned short* xb    = (unsigned short*)(ws + 0);          // 25088*768*2
  unsigned short* wqkvT = (unsigned short*)(ws + 38535168);   // 2304*768*2
  float*          bqkv  = (float*)(ws + 42074112);            // 2304*4
  unsigned short* woT   = (unsigned short*)(ws + 42083328);   // 768*768*2
  unsigned short* qkvb  = (unsigned short*)(ws + 43262976);   // 25088*2304*2
  unsigned short* attnb = (unsigned short*)(ws + 158868480);  // 25088*768*2

  k_prep<<<21120, 256, 0, stream>>>(x, xb, bq, bk, bv, bqkv, Wq, Wk, Wv, Wo, wqkvT, woT);
  k_gemm256<<<882, 512, 0, stream>>>(xb, wqkvT, bqkv, qkvb, 25088, 2304);
  k_attn_fused<<<3120, 256, 0, stream>>>(qkvb, attnb);
  k_gemm_out<<<dim3(6, 196), 256, 0, stream>>>(attnb, woT, bo, out, 25088, 768, 768);
}

// Round 9
// 247.378 us; speedup vs baseline: 1.0516x; 1.0516x over previous
//
#include <hip/hip_runtime.h>

// FactorizedDotProductAttention on MI355X (gfx950)
// B=8, N=3136 (=T16 * P196), C=768, H=12, hd=64. Heads 0-5: spatial attn over P=196
// per (b,t). Heads 6-11: temporal attn over T=16 per (b,p).
// Pipeline: prep (x->bf16 + W packs) ; QKV GEMM (256^2 8-phase, round-4 schedule) ;
// fused attn (round-7 known-good) ; out GEMM (128^2, 3-deep counted-vmcnt pipeline,
// granule-swizzled LDS).

typedef __attribute__((ext_vector_type(8))) short short8;
typedef __attribute__((ext_vector_type(4))) float f32x4;

typedef __attribute__((address_space(1))) void gvoid;
typedef __attribute__((address_space(3))) void lvoid;

__device__ __forceinline__ unsigned short f2b(float f) {
  unsigned int u = __float_as_uint(f);
  unsigned int r = (u + 0x7FFFu + ((u >> 16) & 1u)) >> 16;  // RNE
  return (unsigned short)r;
}

// ---------- kernel 1: prep = convert x (blocks 0..18815) + pack W (blocks 18816..21119) ----------
__global__ __launch_bounds__(256) void k_prep(
    const float* __restrict__ x, unsigned short* __restrict__ xb,
    const float* __restrict__ bq, const float* __restrict__ bk,
    const float* __restrict__ bv, float* __restrict__ bqkv,
    const float* __restrict__ Wq, const float* __restrict__ Wk,
    const float* __restrict__ Wv, const float* __restrict__ Wo,
    unsigned short* __restrict__ wqkvT, unsigned short* __restrict__ woT) {
  __shared__ float tile[32][33];
  if (blockIdx.x < 18816) {
    int tid = blockIdx.x * 256 + threadIdx.x;
    if (tid < 2304)
      bqkv[tid] = tid < 768 ? bq[tid] : (tid < 1536 ? bk[tid - 768] : bv[tid - 1536]);
    float4 v = ((const float4*)x)[tid];
    ushort4 o;
    o.x = f2b(v.x); o.y = f2b(v.y); o.z = f2b(v.z); o.w = f2b(v.w);
    ((ushort4*)xb)[tid] = o;
    return;
  }
  int bid = blockIdx.x - 18816;
  const float* W;
  unsigned short* dst;
  int n0, k0;
  if (bid < 1728) {
    int tn = bid % 72, tk = bid / 72;
    n0 = tn * 32; k0 = tk * 32;
    int which = n0 / 768;
    W = which == 0 ? Wq : (which == 1 ? Wk : Wv);
    dst = wqkvT;
  } else {
    int b2 = bid - 1728;
    int tn = b2 % 24, tk = b2 / 24;
    n0 = tn * 32; k0 = tk * 32;
    W = Wo; dst = woT;
  }
  int nn0 = n0 % 768;
  for (int i = threadIdx.x; i < 1024; i += 256) {
    int r = i >> 5, c = i & 31;
    tile[r][c] = W[(size_t)(k0 + r) * 768 + nn0 + c];
  }
  __syncthreads();
  for (int i = threadIdx.x; i < 1024; i += 256) {
    int r = i >> 5, c = i & 31;
    dst[(size_t)(n0 + r) * 768 + k0 + c] = f2b(tile[c][r]);
  }
}

// ================== 256x256 8-phase GEMM, K=768, 1 barrier/phase ==================
// Round-4 proven schedule (105.5us, MfmaUtil 36.4%). See prior rounds for audit.

#define FENCE asm volatile("" ::: "memory")
#define BARRIER do { FENCE; __builtin_amdgcn_s_barrier(); FENCE; } while (0)
#define WAIT_LGKM0 asm volatile("s_waitcnt lgkmcnt(0)" ::: "memory")
#define WAIT_VM4 asm volatile("s_waitcnt vmcnt(4)" ::: "memory")

#define STAGE(PBASE, BUFBASE, HT, KT_) do {                                          \
    int kt__ = (KT_);                                                                \
    bool real__ = (kt__ < 12);                                                       \
    if (!real__) kt__ -= 12;                                                         \
    const unsigned short* src__ = (PBASE) + (HT) * 98304 + kt__ * 64;                \
    unsigned d0__ = real__ ? ((BUFBASE) + (HT) * 8192 + w * 512) : (65536u + w * 512); \
    unsigned d1__ = real__ ? ((BUFBASE) + (HT) * 8192 + 4096 + w * 512) : (65536u + w * 512); \
    __builtin_amdgcn_global_load_lds((const gvoid*)src__, (lvoid*)(lds + d0__), 16, 0, 0); \
    __builtin_amdgcn_global_load_lds((const gvoid*)(src__ + 49152), (lvoid*)(lds + d1__), 16, 0, 0); \
  } while (0)

#define LDA(MH, ABASE) do {                                                          \
    const unsigned short* ab__ = lds + (ABASE) + ((MH) * 128 + arow) * 64;           \
    _Pragma("unroll")                                                                \
    for (int mf = 0; mf < 4; ++mf) {                                                 \
      af[mf][0] = *(const short8*)(ab__ + mf * 1024 + s0);                           \
      af[mf][1] = *(const short8*)(ab__ + mf * 1024 + s1);                           \
    }                                                                                \
  } while (0)

#define LDB(NH, BBASE) do {                                                          \
    const unsigned short* bb__ = lds + (BBASE) + ((NH) * 128 + brow) * 64;           \
    _Pragma("unroll")                                                                \
    for (int nf = 0; nf < 2; ++nf) {                                                 \
      bf[nf][0] = *(const short8*)(bb__ + nf * 1024 + s0);                           \
      bf[nf][1] = *(const short8*)(bb__ + nf * 1024 + s1);                           \
    }                                                                                \
  } while (0)

#define MM(MH, NH) do {                                                              \
    __builtin_amdgcn_s_setprio(1);                                                   \
    _Pragma("unroll")                                                                \
    for (int mf = 0; mf < 4; ++mf) {                                                 \
      _Pragma("unroll")                                                              \
      for (int nf = 0; nf < 2; ++nf) {                                               \
        acc[MH][mf][NH][nf] = __builtin_amdgcn_mfma_f32_16x16x32_bf16(               \
            af[mf][0], bf[nf][0], acc[MH][mf][NH][nf], 0, 0, 0);                     \
        acc[MH][mf][NH][nf] = __builtin_amdgcn_mfma_f32_16x16x32_bf16(               \
            af[mf][1], bf[nf][1], acc[MH][mf][NH][nf], 0, 0, 0);                     \
      }                                                                              \
    }                                                                                \
    __builtin_amdgcn_s_setprio(0);                                                   \
  } while (0)

__global__ __launch_bounds__(512, 2) void k_gemm256(
    const unsigned short* __restrict__ A, const unsigned short* __restrict__ Bt,
    const float* __restrict__ bias, unsigned short* __restrict__ Cout,
    int M, int N) {
  __shared__ __align__(16) unsigned short lds[69632];
  const int nwg = gridDim.x;
  const int nbx = N >> 8;
  const int orig = blockIdx.x;
  const int q = nwg >> 3, r = nwg & 7;
  const int xcd = orig & 7, lin = orig >> 3;
  const int wg = (xcd < r ? xcd * (q + 1) : r * (q + 1) + (xcd - r) * q) + lin;
  const int m0 = (wg / nbx) << 8, n0 = (wg % nbx) << 8;

  const int tid = threadIdx.x;
  const int w = tid >> 6, l = tid & 63;
  const int wm = w >> 2, wn = w & 3;
  const int lg = l >> 4, ln = l & 15;
  const int arow = wm * 64 + ln;
  const int brow = wn * 32 + ln;
  const int s0 = (lg ^ (ln & 7)) * 8;
  const int s1 = s0 ^ 32;
  const int srow = tid >> 3;
  const int slg8 = ((tid & 7) ^ (srow & 7)) * 8;
  const unsigned short* pA = A + (size_t)(m0 + srow) * 768 + slg8;
  const unsigned short* pB = Bt + (size_t)(n0 + srow) * 768 + slg8;

  f32x4 acc[2][4][2][2] = {};

  STAGE(pA, 0,     0, 0);
  STAGE(pB, 16384, 0, 0);
  STAGE(pA, 0,     1, 0);
  STAGE(pB, 16384, 1, 0);
  STAGE(pA, 32768, 0, 1);
  STAGE(pB, 49152, 1, 1);
  WAIT_VM4;
  BARRIER;

  for (int it = 0; it < 6; ++it) {
    const int kt1 = 2 * it + 1, ktn0 = 2 * it + 2, ktn1 = 2 * it + 3;
    short8 af[4][2], bf[2][2];
    LDA(0, 0); LDB(0, 16384);
    STAGE(pA, 32768, 1, kt1);
    BARRIER; WAIT_LGKM0; MM(0, 0);
    LDB(1, 16384);
    STAGE(pB, 49152, 0, kt1);
    BARRIER; WAIT_LGKM0; MM(0, 1);
    LDA(1, 0);
    STAGE(pA, 0, 0, ktn0);
    BARRIER; WAIT_LGKM0; MM(1, 1);
    LDB(0, 16384);
    STAGE(pB, 16384, 1, ktn0);
    WAIT_VM4;
    BARRIER; WAIT_LGKM0; MM(1, 0);
    LDA(0, 32768); LDB(0, 49152);
    STAGE(pA, 0, 1, ktn0);
    BARRIER; WAIT_LGKM0; MM(0, 0);
    LDB(1, 49152);
    STAGE(pB, 16384, 0, ktn0);
    BARRIER; WAIT_LGKM0; MM(0, 1);
    LDA(1, 32768);
    STAGE(pA, 32768, 0, ktn1);
    BARRIER; WAIT_LGKM0; MM(1, 1);
    LDB(0, 49152);
    STAGE(pB, 49152, 1, ktn1);
    WAIT_VM4;
    BARRIER; WAIT_LGKM0; MM(1, 0);
  }

#pragma unroll
  for (int mh = 0; mh < 2; ++mh)
#pragma unroll
    for (int mf = 0; mf < 4; ++mf)
#pragma unroll
      for (int nh = 0; nh < 2; ++nh)
#pragma unroll
        for (int nf = 0; nf < 2; ++nf) {
          const int col = n0 + nh * 128 + wn * 32 + nf * 16 + ln;
          const float bval = bias[col];
          const int row = m0 + mh * 128 + wm * 64 + mf * 16 + lg * 4;
#pragma unroll
          for (int rr = 0; rr < 4; ++rr)
            Cout[(size_t)(row + rr) * N + col] = f2b(acc[mh][mf][nh][nf][rr] + bval);
        }
}

// ---------- out GEMM: 128x128, BK=32, 3-deep counted-vmcnt pipeline ----------
// LDS: 3 buffers (A 8KB | B 8KB each) + 4KB dummy = 52KB -> 3 blocks/CU.
// Swizzle: 16B granule g of row r stored at g ^ (r&3) (both-sides; cuts the
// ds_read_b128 conflict 8-way -> 4-way; full spread impossible with 4 slots/row
// under gload_lds's linear-dest constraint).
// Pipeline: stage(i+2) issued while computing i; wait vmcnt(4) retires exactly
// tile (i+1)'s 4 loads (stage(i+2)'s 4 stay in flight) -> never drains to 0.
// Tail uses dummy-redirect stages to keep the count uniform.
__global__ __launch_bounds__(256) void k_gemm_out(
    const unsigned short* __restrict__ A, const unsigned short* __restrict__ Bt,
    const float* __restrict__ bias, float* __restrict__ C,
    int M, int N, int K) {
  __shared__ __align__(16) unsigned short lds[26624];  // 3*8192 + 2048 dummy (shorts)
  const int tid = threadIdx.x;
  const int w = tid >> 6, l = tid & 63;
  const int lg = l >> 4, ln = l & 15;
  const int m0 = blockIdx.y * 128, n0 = blockIdx.x * 128;
  const int wr = (w >> 1) * 64, wc = (w & 1) * 64;
  f32x4 acc[4][4] = {};
  const int srow = tid >> 2;
  const int sg = ((tid & 3) ^ (srow & 3)) * 8;  // pre-swizzled source granule
  const unsigned short* ga = A + (size_t)(m0 + srow) * K + sg;
  const unsigned short* gb = Bt + (size_t)(n0 + srow) * K + sg;
  const size_t krow64 = (size_t)64 * K;
  const int wofs = w * 512;                     // shorts
  const int rs = (lg ^ (ln & 3)) * 8;           // swizzled read slot (elems)

#define OSTAGE3(BUF, K0, REAL) do {                                                                \
    int k__ = (REAL) ? (K0) : 0;                                                                   \
    unsigned a__ = (REAL) ? ((unsigned)(BUF) * 8192u + wofs) : (24576u + wofs);                    \
    unsigned b__ = (REAL) ? ((unsigned)(BUF) * 8192u + 4096u + wofs) : (24576u + wofs);            \
    __builtin_amdgcn_global_load_lds((const gvoid*)(ga + k__),          (lvoid*)(lds + a__),        16, 0, 0); \
    __builtin_amdgcn_global_load_lds((const gvoid*)(ga + krow64 + k__), (lvoid*)(lds + a__ + 2048), 16, 0, 0); \
    __builtin_amdgcn_global_load_lds((const gvoid*)(gb + k__),          (lvoid*)(lds + b__),        16, 0, 0); \
    __builtin_amdgcn_global_load_lds((const gvoid*)(gb + krow64 + k__), (lvoid*)(lds + b__ + 2048), 16, 0, 0); \
  } while (0)

  OSTAGE3(0, 0, true);
  OSTAGE3(1, 32, true);
  WAIT_VM4;  // buf0 landed (buf1's 4 still in flight)
  BARRIER;
  int bcur = 0, bnxt = 1, bpre = 2;
  const int nk = K >> 5;  // 24
  for (int i = 0; i < nk; ++i) {
    OSTAGE3(bpre, (i + 2) * 32, i + 2 < nk);
    const unsigned short* as = lds + bcur * 8192;
    const unsigned short* bs = as + 4096;
    short8 a[4], b[4];
#pragma unroll
    for (int mt = 0; mt < 4; ++mt)
      a[mt] = *(const short8*)(as + (wr + mt * 16 + ln) * 32 + rs);
#pragma unroll
    for (int nt = 0; nt < 4; ++nt)
      b[nt] = *(const short8*)(bs + (wc + nt * 16 + ln) * 32 + rs);
#pragma unroll
    for (int mt = 0; mt < 4; ++mt)
#pragma unroll
      for (int nt = 0; nt < 4; ++nt)
        acc[mt][nt] = __builtin_amdgcn_mfma_f32_16x16x32_bf16(a[mt], b[nt], acc[mt][nt], 0, 0, 0);
    WAIT_VM4;  // retire tile (i+1)'s loads; tile (i+2)'s stay in flight
    BARRIER;
    int t = bcur; bcur = bnxt; bnxt = bpre; bpre = t;
  }
#pragma unroll
  for (int nt = 0; nt < 4; ++nt) {
    int col = n0 + wc + nt * 16 + ln;
    float bval = bias[col];
#pragma unroll
    for (int mt = 0; mt < 4; ++mt) {
      int row = m0 + wr + mt * 16 + lg * 4;
#pragma unroll
      for (int r = 0; r < 4; ++r)
        C[(size_t)(row + r) * N + col] = acc[mt][nt][r] + bval;
    }
  }
#undef OSTAGE3
}

// ---------- fused attention (round-7 known-good) ----------
// blocks 0..767: spatial, one block per (b,t,h). blocks 768..3119: temporal,
// one wave per (b,p,h). V staged with short8 vector global loads + transposed
// scalar ds_writes.
__global__ __launch_bounds__(256) void k_attn_fused(
    const unsigned short* __restrict__ qkv, unsigned short* __restrict__ attn) {
  __shared__ __align__(16) unsigned short smem[29696];  // 59392 B
  const int w = threadIdx.x >> 6, l = threadIdx.x & 63;
  const int lg = l >> 4, ln = l & 15;
  const float scale = 0.125f;
  if (blockIdx.x < 768) {
    // ---- spatial: heads 0-5 ----
    const int bi = blockIdx.x;
    const int h = bi % 6;
    const int t = (bi / 6) % 16;
    const int b = bi / 96;
    const int base_row = b * 3136 + t * 196;
    unsigned short* Vt = smem;           // [64][232]
    unsigned short* Pl = smem + 14848;   // [4][16][232]
    for (int i = threadIdx.x; i < 196 * 8; i += 256) {
      int key = i >> 3, d0 = (i & 7) * 8;
      short8 v = *(const short8*)(qkv + (size_t)(base_row + key) * 2304 + 1536 + h * 64 + d0);
#pragma unroll
      for (int j = 0; j < 8; ++j) Vt[(d0 + j) * 232 + key] = (unsigned short)v[j];
    }
    for (int i = threadIdx.x; i < 64 * 28; i += 256)
      Vt[(i / 28) * 232 + 196 + (i % 28)] = 0;
    __syncthreads();
    for (int mt = w; mt < 13; mt += 4) {
      int qm = mt * 16 + ln; if (qm > 195) qm = 195;
      const size_t qoff = (size_t)(base_row + qm) * 2304 + h * 64 + lg * 8;
      short8 qa0 = *(const short8*)(qkv + qoff);
      short8 qa1 = *(const short8*)(qkv + qoff + 32);
      f32x4 st[13];
#pragma unroll
      for (int nt = 0; nt < 13; ++nt) {
        int kn = nt * 16 + ln; if (kn > 195) kn = 195;
        const size_t koff = (size_t)(base_row + kn) * 2304 + 768 + h * 64 + lg * 8;
        short8 kb0 = *(const short8*)(qkv + koff);
        short8 kb1 = *(const short8*)(qkv + koff + 32);
        f32x4 s = {0.f, 0.f, 0.f, 0.f};
        s = __builtin_amdgcn_mfma_f32_16x16x32_bf16(qa0, kb0, s, 0, 0, 0);
        s = __builtin_amdgcn_mfma_f32_16x16x32_bf16(qa1, kb1, s, 0, 0, 0);
        st[nt] = s;
      }
      float mr[4] = {-1e30f, -1e30f, -1e30f, -1e30f};
#pragma unroll
      for (int nt = 0; nt < 13; ++nt) {
        bool valid = (nt * 16 + ln) < 196;
#pragma unroll
        for (int r = 0; r < 4; ++r) {
          float v = valid ? st[nt][r] * scale : -1e30f;
          st[nt][r] = v;
          mr[r] = fmaxf(mr[r], v);
        }
      }
#pragma unroll
      for (int msk = 1; msk <= 8; msk <<= 1)
#pragma unroll
        for (int r = 0; r < 4; ++r) mr[r] = fmaxf(mr[r], __shfl_xor(mr[r], msk));
      float sm[4] = {0.f, 0.f, 0.f, 0.f};
#pragma unroll
      for (int nt = 0; nt < 13; ++nt)
#pragma unroll
        for (int r = 0; r < 4; ++r) {
          float p = __expf(st[nt][r] - mr[r]);
          st[nt][r] = p;
          sm[r] += p;
        }
#pragma unroll
      for (int msk = 1; msk <= 8; msk <<= 1)
#pragma unroll
        for (int r = 0; r < 4; ++r) sm[r] += __shfl_xor(sm[r], msk);
      float inv[4];
#pragma unroll
      for (int r = 0; r < 4; ++r) inv[r] = 1.f / sm[r];
      unsigned short* Pw = Pl + w * 16 * 232;
#pragma unroll
      for (int nt = 0; nt < 13; ++nt)
#pragma unroll
        for (int r = 0; r < 4; ++r)
          Pw[(lg * 4 + r) * 232 + nt * 16 + ln] = f2b(st[nt][r] * inv[r]);
#pragma unroll
      for (int r = 0; r < 4; ++r) Pw[ln * 232 + 208 + lg * 4 + r] = 0;
#pragma unroll
      for (int nt4 = 0; nt4 < 4; ++nt4) {
        f32x4 acc = {0.f, 0.f, 0.f, 0.f};
#pragma unroll
        for (int ks = 0; ks < 7; ++ks) {
          short8 pa = *(const short8*)(Pw + ln * 232 + ks * 32 + lg * 8);
          short8 vb = *(const short8*)(Vt + (nt4 * 16 + ln) * 232 + ks * 32 + lg * 8);
          acc = __builtin_amdgcn_mfma_f32_16x16x32_bf16(pa, vb, acc, 0, 0, 0);
        }
#pragma unroll
        for (int r = 0; r < 4; ++r) {
          int m = mt * 16 + lg * 4 + r;
          if (m < 196)
            attn[(size_t)(base_row + m) * 768 + h * 64 + nt4 * 16 + ln] = f2b(acc[r]);
        }
      }
    }
  } else {
    // ---- temporal: heads 6-11, one wave per (b,p,h) ----
    const int u = (blockIdx.x - 768) * 4 + w;  // 9408 = 8*196*6
    const int b = u / 1176;
    const int rem = u % 1176;
    const int p = rem / 6;
    const int h = 6 + rem % 6;
    const size_t rowb = (size_t)b * 3136 + p;
    unsigned short* Vt = smem + w * 2560;          // [64][40]
    unsigned short* Pl = smem + 10240 + w * 640;   // [16][40]
    for (int i = l; i < 128; i += 64) {
      int tt = i >> 3, d0 = (i & 7) * 8;
      short8 v = *(const short8*)(qkv + (rowb + (size_t)tt * 196) * 2304 + 1536 + h * 64 + d0);
#pragma unroll
      for (int j = 0; j < 8; ++j) Vt[(d0 + j) * 40 + tt] = (unsigned short)v[j];
    }
    for (int i = l; i < 1024; i += 64)
      Vt[(i >> 4) * 40 + 16 + (i & 15)] = 0;
    const size_t qoff = (rowb + (size_t)ln * 196) * 2304 + h * 64 + lg * 8;
    short8 qa0 = *(const short8*)(qkv + qoff);
    short8 qa1 = *(const short8*)(qkv + qoff + 32);
    short8 kb0 = *(const short8*)(qkv + qoff + 768);
    short8 kb1 = *(const short8*)(qkv + qoff + 768 + 32);
    f32x4 s = {0.f, 0.f, 0.f, 0.f};
    s = __builtin_amdgcn_mfma_f32_16x16x32_bf16(qa0, kb0, s, 0, 0, 0);
    s = __builtin_amdgcn_mfma_f32_16x16x32_bf16(qa1, kb1, s, 0, 0, 0);
    float stv[4], mr[4];
#pragma unroll
    for (int r = 0; r < 4; ++r) { stv[r] = s[r] * scale; mr[r] = stv[r]; }
#pragma unroll
    for (int msk = 1; msk <= 8; msk <<= 1)
#pragma unroll
      for (int r = 0; r < 4; ++r) mr[r] = fmaxf(mr[r], __shfl_xor(mr[r], msk));
    float sm[4];
#pragma unroll
    for (int r = 0; r < 4; ++r) { stv[r] = __expf(stv[r] - mr[r]); sm[r] = stv[r]; }
#pragma unroll
    for (int msk = 1; msk <= 8; msk <<= 1)
#pragma unroll
      for (int r = 0; r < 4; ++r) sm[r] += __shfl_xor(sm[r], msk);
#pragma unroll
    for (int r = 0; r < 4; ++r)
      Pl[(lg * 4 + r) * 40 + ln] = f2b(stv[r] / sm[r]);
#pragma unroll
    for (int r = 0; r < 4; ++r) Pl[ln * 40 + 16 + lg * 4 + r] = 0;
    short8 pa = *(const short8*)(Pl + ln * 40 + lg * 8);
#pragma unroll
    for (int nt4 = 0; nt4 < 4; ++nt4) {
      short8 vb = *(const short8*)(Vt + (nt4 * 16 + ln) * 40 + lg * 8);
      f32x4 acc = {0.f, 0.f, 0.f, 0.f};
      acc = __builtin_amdgcn_mfma_f32_16x16x32_bf16(pa, vb, acc, 0, 0, 0);
#pragma unroll
      for (int r = 0; r < 4; ++r) {
        int tq = lg * 4 + r;
        attn[((size_t)b * 3136 + (size_t)tq * 196 + p) * 768 + h * 64 + nt4 * 16 + ln] = f2b(acc[r]);
      }
    }
  }
}

// ---------- launch ----------
extern "C" void kernel_launch(void* const* d_in, const int* in_sizes, int n_in,
                              void* d_out, int out_size, void* d_ws, size_t ws_size,
                              hipStream_t stream) {
  const float* x  = (const float*)d_in[0];
  const float* Wq = (const float*)d_in[1];
  const float* bq = (const float*)d_in[2];
  const float* Wk = (const float*)d_in[3];
  const float* bk = (const float*)d_in[4];
  const float* Wv = (const float*)d_in[5];
  const float* bv = (const float*)d_in[6];
  const float* Wo = (const float*)d_in[7];
  const float* bo = (const float*)d_in[8];
  float* out = (float*)d_out;
  char* ws = (char*)d_ws;
  unsigned short* xb    = (unsigned short*)(ws + 0);          // 25088*768*2
  unsigned short* wqkvT = (unsigned short*)(ws + 38535168);   // 2304*768*2
  float*          bqkv  = (float*)(ws + 42074112);            // 2304*4
  unsigned short* woT   = (unsigned short*)(ws + 42083328);   // 768*768*2
  unsigned short* qkvb  = (unsigned short*)(ws + 43262976);   // 25088*2304*2
  unsigned short* attnb = (unsigned short*)(ws + 158868480);  // 25088*768*2

  k_prep<<<21120, 256, 0, stream>>>(x, xb, bq, bk, bv, bqkv, Wq, Wk, Wv, Wo, wqkvT, woT);
  k_gemm256<<<882, 512, 0, stream>>>(xb, wqkvT, bqkv, qkvb, 25088, 2304);
  k_attn_fused<<<3120, 256, 0, stream>>>(qkvb, attnb);
  k_gemm_out<<<dim3(6, 196), 256, 0, stream>>>(attnb, woT, bo, out, 25088, 768, 768);
}

// Round 10
// 244.539 us; speedup vs baseline: 1.0638x; 1.0116x over previous
//
#include <hip/hip_runtime.h>

// FactorizedDotProductAttention on MI355X (gfx950)
// B=8, N=3136 (=T16 * P196), C=768, H=12, hd=64. Heads 0-5: spatial attn over P=196
// per (b,t). Heads 6-11: temporal attn over T=16 per (b,p).
// Pipeline: prep (x->bf16 + W packs) ; QKV GEMM (256^2 8-phase, round-4 schedule) ;
// fused attn (round-7 known-good) ; out GEMM (128x192 dbuf, 784 blocks = 1 resident
// round at 3 blocks/CU).

typedef __attribute__((ext_vector_type(8))) short short8;
typedef __attribute__((ext_vector_type(4))) float f32x4;

typedef __attribute__((address_space(1))) void gvoid;
typedef __attribute__((address_space(3))) void lvoid;

__device__ __forceinline__ unsigned short f2b(float f) {
  unsigned int u = __float_as_uint(f);
  unsigned int r = (u + 0x7FFFu + ((u >> 16) & 1u)) >> 16;  // RNE
  return (unsigned short)r;
}

// ---------- kernel 1: prep = convert x (blocks 0..18815) + pack W (blocks 18816..21119) ----------
__global__ __launch_bounds__(256) void k_prep(
    const float* __restrict__ x, unsigned short* __restrict__ xb,
    const float* __restrict__ bq, const float* __restrict__ bk,
    const float* __restrict__ bv, float* __restrict__ bqkv,
    const float* __restrict__ Wq, const float* __restrict__ Wk,
    const float* __restrict__ Wv, const float* __restrict__ Wo,
    unsigned short* __restrict__ wqkvT, unsigned short* __restrict__ woT) {
  __shared__ float tile[32][33];
  if (blockIdx.x < 18816) {
    int tid = blockIdx.x * 256 + threadIdx.x;
    if (tid < 2304)
      bqkv[tid] = tid < 768 ? bq[tid] : (tid < 1536 ? bk[tid - 768] : bv[tid - 1536]);
    float4 v = ((const float4*)x)[tid];
    ushort4 o;
    o.x = f2b(v.x); o.y = f2b(v.y); o.z = f2b(v.z); o.w = f2b(v.w);
    ((ushort4*)xb)[tid] = o;
    return;
  }
  int bid = blockIdx.x - 18816;
  const float* W;
  unsigned short* dst;
  int n0, k0;
  if (bid < 1728) {
    int tn = bid % 72, tk = bid / 72;
    n0 = tn * 32; k0 = tk * 32;
    int which = n0 / 768;
    W = which == 0 ? Wq : (which == 1 ? Wk : Wv);
    dst = wqkvT;
  } else {
    int b2 = bid - 1728;
    int tn = b2 % 24, tk = b2 / 24;
    n0 = tn * 32; k0 = tk * 32;
    W = Wo; dst = woT;
  }
  int nn0 = n0 % 768;
  for (int i = threadIdx.x; i < 1024; i += 256) {
    int r = i >> 5, c = i & 31;
    tile[r][c] = W[(size_t)(k0 + r) * 768 + nn0 + c];
  }
  __syncthreads();
  for (int i = threadIdx.x; i < 1024; i += 256) {
    int r = i >> 5, c = i & 31;
    dst[(size_t)(n0 + r) * 768 + k0 + c] = f2b(tile[c][r]);
  }
}

// ================== 256x256 8-phase GEMM, K=768, 1 barrier/phase ==================
// Round-4 proven schedule (105.5us, MfmaUtil 36.4%). See prior rounds for audit.

#define FENCE asm volatile("" ::: "memory")
#define BARRIER do { FENCE; __builtin_amdgcn_s_barrier(); FENCE; } while (0)
#define WAIT_LGKM0 asm volatile("s_waitcnt lgkmcnt(0)" ::: "memory")
#define WAIT_VM4 asm volatile("s_waitcnt vmcnt(4)" ::: "memory")

#define STAGE(PBASE, BUFBASE, HT, KT_) do {                                          \
    int kt__ = (KT_);                                                                \
    bool real__ = (kt__ < 12);                                                       \
    if (!real__) kt__ -= 12;                                                         \
    const unsigned short* src__ = (PBASE) + (HT) * 98304 + kt__ * 64;                \
    unsigned d0__ = real__ ? ((BUFBASE) + (HT) * 8192 + w * 512) : (65536u + w * 512); \
    unsigned d1__ = real__ ? ((BUFBASE) + (HT) * 8192 + 4096 + w * 512) : (65536u + w * 512); \
    __builtin_amdgcn_global_load_lds((const gvoid*)src__, (lvoid*)(lds + d0__), 16, 0, 0); \
    __builtin_amdgcn_global_load_lds((const gvoid*)(src__ + 49152), (lvoid*)(lds + d1__), 16, 0, 0); \
  } while (0)

#define LDA(MH, ABASE) do {                                                          \
    const unsigned short* ab__ = lds + (ABASE) + ((MH) * 128 + arow) * 64;           \
    _Pragma("unroll")                                                                \
    for (int mf = 0; mf < 4; ++mf) {                                                 \
      af[mf][0] = *(const short8*)(ab__ + mf * 1024 + s0);                           \
      af[mf][1] = *(const short8*)(ab__ + mf * 1024 + s1);                           \
    }                                                                                \
  } while (0)

#define LDB(NH, BBASE) do {                                                          \
    const unsigned short* bb__ = lds + (BBASE) + ((NH) * 128 + brow) * 64;           \
    _Pragma("unroll")                                                                \
    for (int nf = 0; nf < 2; ++nf) {                                                 \
      bf[nf][0] = *(const short8*)(bb__ + nf * 1024 + s0);                           \
      bf[nf][1] = *(const short8*)(bb__ + nf * 1024 + s1);                           \
    }                                                                                \
  } while (0)

#define MM(MH, NH) do {                                                              \
    __builtin_amdgcn_s_setprio(1);                                                   \
    _Pragma("unroll")                                                                \
    for (int mf = 0; mf < 4; ++mf) {                                                 \
      _Pragma("unroll")                                                              \
      for (int nf = 0; nf < 2; ++nf) {                                               \
        acc[MH][mf][NH][nf] = __builtin_amdgcn_mfma_f32_16x16x32_bf16(               \
            af[mf][0], bf[nf][0], acc[MH][mf][NH][nf], 0, 0, 0);                     \
        acc[MH][mf][NH][nf] = __builtin_amdgcn_mfma_f32_16x16x32_bf16(               \
            af[mf][1], bf[nf][1], acc[MH][mf][NH][nf], 0, 0, 0);                     \
      }                                                                              \
    }                                                                                \
    __builtin_amdgcn_s_setprio(0);                                                   \
  } while (0)

__global__ __launch_bounds__(512, 2) void k_gemm256(
    const unsigned short* __restrict__ A, const unsigned short* __restrict__ Bt,
    const float* __restrict__ bias, unsigned short* __restrict__ Cout,
    int M, int N) {
  __shared__ __align__(16) unsigned short lds[69632];
  const int nwg = gridDim.x;
  const int nbx = N >> 8;
  const int orig = blockIdx.x;
  const int q = nwg >> 3, r = nwg & 7;
  const int xcd = orig & 7, lin = orig >> 3;
  const int wg = (xcd < r ? xcd * (q + 1) : r * (q + 1) + (xcd - r) * q) + lin;
  const int m0 = (wg / nbx) << 8, n0 = (wg % nbx) << 8;

  const int tid = threadIdx.x;
  const int w = tid >> 6, l = tid & 63;
  const int wm = w >> 2, wn = w & 3;
  const int lg = l >> 4, ln = l & 15;
  const int arow = wm * 64 + ln;
  const int brow = wn * 32 + ln;
  const int s0 = (lg ^ (ln & 7)) * 8;
  const int s1 = s0 ^ 32;
  const int srow = tid >> 3;
  const int slg8 = ((tid & 7) ^ (srow & 7)) * 8;
  const unsigned short* pA = A + (size_t)(m0 + srow) * 768 + slg8;
  const unsigned short* pB = Bt + (size_t)(n0 + srow) * 768 + slg8;

  f32x4 acc[2][4][2][2] = {};

  STAGE(pA, 0,     0, 0);
  STAGE(pB, 16384, 0, 0);
  STAGE(pA, 0,     1, 0);
  STAGE(pB, 16384, 1, 0);
  STAGE(pA, 32768, 0, 1);
  STAGE(pB, 49152, 1, 1);
  WAIT_VM4;
  BARRIER;

  for (int it = 0; it < 6; ++it) {
    const int kt1 = 2 * it + 1, ktn0 = 2 * it + 2, ktn1 = 2 * it + 3;
    short8 af[4][2], bf[2][2];
    LDA(0, 0); LDB(0, 16384);
    STAGE(pA, 32768, 1, kt1);
    BARRIER; WAIT_LGKM0; MM(0, 0);
    LDB(1, 16384);
    STAGE(pB, 49152, 0, kt1);
    BARRIER; WAIT_LGKM0; MM(0, 1);
    LDA(1, 0);
    STAGE(pA, 0, 0, ktn0);
    BARRIER; WAIT_LGKM0; MM(1, 1);
    LDB(0, 16384);
    STAGE(pB, 16384, 1, ktn0);
    WAIT_VM4;
    BARRIER; WAIT_LGKM0; MM(1, 0);
    LDA(0, 32768); LDB(0, 49152);
    STAGE(pA, 0, 1, ktn0);
    BARRIER; WAIT_LGKM0; MM(0, 0);
    LDB(1, 49152);
    STAGE(pB, 16384, 0, ktn0);
    BARRIER; WAIT_LGKM0; MM(0, 1);
    LDA(1, 32768);
    STAGE(pA, 32768, 0, ktn1);
    BARRIER; WAIT_LGKM0; MM(1, 1);
    LDB(0, 49152);
    STAGE(pB, 49152, 1, ktn1);
    WAIT_VM4;
    BARRIER; WAIT_LGKM0; MM(1, 0);
  }

#pragma unroll
  for (int mh = 0; mh < 2; ++mh)
#pragma unroll
    for (int mf = 0; mf < 4; ++mf)
#pragma unroll
      for (int nh = 0; nh < 2; ++nh)
#pragma unroll
        for (int nf = 0; nf < 2; ++nf) {
          const int col = n0 + nh * 128 + wn * 32 + nf * 16 + ln;
          const float bval = bias[col];
          const int row = m0 + mh * 128 + wm * 64 + mf * 16 + lg * 4;
#pragma unroll
          for (int rr = 0; rr < 4; ++rr)
            Cout[(size_t)(row + rr) * N + col] = f2b(acc[mh][mf][nh][nf][rr] + bval);
        }
}

// ---------- out GEMM: 128x192 tile, BK=32, double-buffered ----------
// Grid = 196 x 4 = 784 blocks; at 3 blocks/CU (LDS 44KB, launch_bounds(256,3))
// 768 are co-resident -> ~1 dispatch round (vs 2 rounds for 1176-block 128^2).
// 4 waves (2m x 2n), wave tile 64x96, acc[4][6]. Swizzle: 16B granule g of row r
// at g ^ (r&3), both-sides. Stage(next) issued before compute(cur); vmcnt(0)
// drain overlaps the 24-MFMA compute phase.
__global__ __launch_bounds__(256, 3) void k_gemm_out(
    const unsigned short* __restrict__ A, const unsigned short* __restrict__ Bt,
    const float* __restrict__ bias, float* __restrict__ C,
    int M, int N, int K) {
  __shared__ __align__(16) unsigned short lds[22528];  // 2 x (A 4096 + B 6144) + 2048 dummy
  const int tid = threadIdx.x;
  const int w = tid >> 6, l = tid & 63;
  const int lg = l >> 4, ln = l & 15;
  const int m0 = blockIdx.y * 128, n0 = blockIdx.x * 192;
  const int wr = (w >> 1) * 64, wc = (w & 1) * 96;
  f32x4 acc[4][6] = {};
  const int srow = tid >> 2;                    // 0..63
  const int sg = ((tid & 3) ^ (srow & 3)) * 8;  // pre-swizzled source granule
  const unsigned short* ga = A + (size_t)(m0 + srow) * K + sg;
  const unsigned short* gb = Bt + (size_t)(n0 + srow) * K + sg;
  const int wofs = w * 512;                     // shorts
  const int rs = (lg ^ (ln & 3)) * 8;           // swizzled read slot (elems)

#define OSTAGE(BUF, K0) do {                                                                       \
    const unsigned base__ = (unsigned)(BUF) * 10240u;                                              \
    _Pragma("unroll")                                                                              \
    for (int j = 0; j < 2; ++j)                                                                    \
      __builtin_amdgcn_global_load_lds((const gvoid*)(ga + (size_t)(j * 64) * K + (K0)),           \
                                       (lvoid*)(lds + base__ + j * 2048 + wofs), 16, 0, 0);        \
    _Pragma("unroll")                                                                              \
    for (int j = 0; j < 3; ++j)                                                                    \
      __builtin_amdgcn_global_load_lds((const gvoid*)(gb + (size_t)(j * 64) * K + (K0)),           \
                                       (lvoid*)(lds + base__ + 4096 + j * 2048 + wofs), 16, 0, 0); \
  } while (0)

  OSTAGE(0, 0);
  asm volatile("s_waitcnt vmcnt(0)" ::: "memory");
  BARRIER;
  const int nk = K >> 5;  // 24
  for (int i = 0; i < nk; ++i) {
    if (i + 1 < nk) OSTAGE((i + 1) & 1, (i + 1) * 32);  // prefetch next tile
    const unsigned short* as = lds + (i & 1) * 10240;
    const unsigned short* bs = as + 4096;
    short8 a[4], b[6];
#pragma unroll
    for (int mt = 0; mt < 4; ++mt)
      a[mt] = *(const short8*)(as + (wr + mt * 16 + ln) * 32 + rs);
#pragma unroll
    for (int nt = 0; nt < 6; ++nt)
      b[nt] = *(const short8*)(bs + (wc + nt * 16 + ln) * 32 + rs);
#pragma unroll
    for (int mt = 0; mt < 4; ++mt)
#pragma unroll
      for (int nt = 0; nt < 6; ++nt)
        acc[mt][nt] = __builtin_amdgcn_mfma_f32_16x16x32_bf16(a[mt], b[nt], acc[mt][nt], 0, 0, 0);
    asm volatile("s_waitcnt vmcnt(0)" ::: "memory");  // next-tile loads landed (overlapped)
    BARRIER;
  }
#pragma unroll
  for (int nt = 0; nt < 6; ++nt) {
    int col = n0 + wc + nt * 16 + ln;
    float bval = bias[col];
#pragma unroll
    for (int mt = 0; mt < 4; ++mt) {
      int row = m0 + wr + mt * 16 + lg * 4;
#pragma unroll
      for (int r = 0; r < 4; ++r)
        C[(size_t)(row + r) * N + col] = acc[mt][nt][r] + bval;
    }
  }
#undef OSTAGE
}

// ---------- fused attention (round-7 known-good) ----------
// blocks 0..767: spatial, one block per (b,t,h). blocks 768..3119: temporal,
// one wave per (b,p,h). V staged with short8 vector global loads + transposed
// scalar ds_writes.
__global__ __launch_bounds__(256) void k_attn_fused(
    const unsigned short* __restrict__ qkv, unsigned short* __restrict__ attn) {
  __shared__ __align__(16) unsigned short smem[29696];  // 59392 B
  const int w = threadIdx.x >> 6, l = threadIdx.x & 63;
  const int lg = l >> 4, ln = l & 15;
  const float scale = 0.125f;
  if (blockIdx.x < 768) {
    // ---- spatial: heads 0-5 ----
    const int bi = blockIdx.x;
    const int h = bi % 6;
    const int t = (bi / 6) % 16;
    const int b = bi / 96;
    const int base_row = b * 3136 + t * 196;
    unsigned short* Vt = smem;           // [64][232]
    unsigned short* Pl = smem + 14848;   // [4][16][232]
    for (int i = threadIdx.x; i < 196 * 8; i += 256) {
      int key = i >> 3, d0 = (i & 7) * 8;
      short8 v = *(const short8*)(qkv + (size_t)(base_row + key) * 2304 + 1536 + h * 64 + d0);
#pragma unroll
      for (int j = 0; j < 8; ++j) Vt[(d0 + j) * 232 + key] = (unsigned short)v[j];
    }
    for (int i = threadIdx.x; i < 64 * 28; i += 256)
      Vt[(i / 28) * 232 + 196 + (i % 28)] = 0;
    __syncthreads();
    for (int mt = w; mt < 13; mt += 4) {
      int qm = mt * 16 + ln; if (qm > 195) qm = 195;
      const size_t qoff = (size_t)(base_row + qm) * 2304 + h * 64 + lg * 8;
      short8 qa0 = *(const short8*)(qkv + qoff);
      short8 qa1 = *(const short8*)(qkv + qoff + 32);
      f32x4 st[13];
#pragma unroll
      for (int nt = 0; nt < 13; ++nt) {
        int kn = nt * 16 + ln; if (kn > 195) kn = 195;
        const size_t koff = (size_t)(base_row + kn) * 2304 + 768 + h * 64 + lg * 8;
        short8 kb0 = *(const short8*)(qkv + koff);
        short8 kb1 = *(const short8*)(qkv + koff + 32);
        f32x4 s = {0.f, 0.f, 0.f, 0.f};
        s = __builtin_amdgcn_mfma_f32_16x16x32_bf16(qa0, kb0, s, 0, 0, 0);
        s = __builtin_amdgcn_mfma_f32_16x16x32_bf16(qa1, kb1, s, 0, 0, 0);
        st[nt] = s;
      }
      float mr[4] = {-1e30f, -1e30f, -1e30f, -1e30f};
#pragma unroll
      for (int nt = 0; nt < 13; ++nt) {
        bool valid = (nt * 16 + ln) < 196;
#pragma unroll
        for (int r = 0; r < 4; ++r) {
          float v = valid ? st[nt][r] * scale : -1e30f;
          st[nt][r] = v;
          mr[r] = fmaxf(mr[r], v);
        }
      }
#pragma unroll
      for (int msk = 1; msk <= 8; msk <<= 1)
#pragma unroll
        for (int r = 0; r < 4; ++r) mr[r] = fmaxf(mr[r], __shfl_xor(mr[r], msk));
      float sm[4] = {0.f, 0.f, 0.f, 0.f};
#pragma unroll
      for (int nt = 0; nt < 13; ++nt)
#pragma unroll
        for (int r = 0; r < 4; ++r) {
          float p = __expf(st[nt][r] - mr[r]);
          st[nt][r] = p;
          sm[r] += p;
        }
#pragma unroll
      for (int msk = 1; msk <= 8; msk <<= 1)
#pragma unroll
        for (int r = 0; r < 4; ++r) sm[r] += __shfl_xor(sm[r], msk);
      float inv[4];
#pragma unroll
      for (int r = 0; r < 4; ++r) inv[r] = 1.f / sm[r];
      unsigned short* Pw = Pl + w * 16 * 232;
#pragma unroll
      for (int nt = 0; nt < 13; ++nt)
#pragma unroll
        for (int r = 0; r < 4; ++r)
          Pw[(lg * 4 + r) * 232 + nt * 16 + ln] = f2b(st[nt][r] * inv[r]);
#pragma unroll
      for (int r = 0; r < 4; ++r) Pw[ln * 232 + 208 + lg * 4 + r] = 0;
#pragma unroll
      for (int nt4 = 0; nt4 < 4; ++nt4) {
        f32x4 acc = {0.f, 0.f, 0.f, 0.f};
#pragma unroll
        for (int ks = 0; ks < 7; ++ks) {
          short8 pa = *(const short8*)(Pw + ln * 232 + ks * 32 + lg * 8);
          short8 vb = *(const short8*)(Vt + (nt4 * 16 + ln) * 232 + ks * 32 + lg * 8);
          acc = __builtin_amdgcn_mfma_f32_16x16x32_bf16(pa, vb, acc, 0, 0, 0);
        }
#pragma unroll
        for (int r = 0; r < 4; ++r) {
          int m = mt * 16 + lg * 4 + r;
          if (m < 196)
            attn[(size_t)(base_row + m) * 768 + h * 64 + nt4 * 16 + ln] = f2b(acc[r]);
        }
      }
    }
  } else {
    // ---- temporal: heads 6-11, one wave per (b,p,h) ----
    const int u = (blockIdx.x - 768) * 4 + w;  // 9408 = 8*196*6
    const int b = u / 1176;
    const int rem = u % 1176;
    const int p = rem / 6;
    const int h = 6 + rem % 6;
    const size_t rowb = (size_t)b * 3136 + p;
    unsigned short* Vt = smem + w * 2560;          // [64][40]
    unsigned short* Pl = smem + 10240 + w * 640;   // [16][40]
    for (int i = l; i < 128; i += 64) {
      int tt = i >> 3, d0 = (i & 7) * 8;
      short8 v = *(const short8*)(qkv + (rowb + (size_t)tt * 196) * 2304 + 1536 + h * 64 + d0);
#pragma unroll
      for (int j = 0; j < 8; ++j) Vt[(d0 + j) * 40 + tt] = (unsigned short)v[j];
    }
    for (int i = l; i < 1024; i += 64)
      Vt[(i >> 4) * 40 + 16 + (i & 15)] = 0;
    const size_t qoff = (rowb + (size_t)ln * 196) * 2304 + h * 64 + lg * 8;
    short8 qa0 = *(const short8*)(qkv + qoff);
    short8 qa1 = *(const short8*)(qkv + qoff + 32);
    short8 kb0 = *(const short8*)(qkv + qoff + 768);
    short8 kb1 = *(const short8*)(qkv + qoff + 768 + 32);
    f32x4 s = {0.f, 0.f, 0.f, 0.f};
    s = __builtin_amdgcn_mfma_f32_16x16x32_bf16(qa0, kb0, s, 0, 0, 0);
    s = __builtin_amdgcn_mfma_f32_16x16x32_bf16(qa1, kb1, s, 0, 0, 0);
    float stv[4], mr[4];
#pragma unroll
    for (int r = 0; r < 4; ++r) { stv[r] = s[r] * scale; mr[r] = stv[r]; }
#pragma unroll
    for (int msk = 1; msk <= 8; msk <<= 1)
#pragma unroll
      for (int r = 0; r < 4; ++r) mr[r] = fmaxf(mr[r], __shfl_xor(mr[r], msk));
    float sm[4];
#pragma unroll
    for (int r = 0; r < 4; ++r) { stv[r] = __expf(stv[r] - mr[r]); sm[r] = stv[r]; }
#pragma unroll
    for (int msk = 1; msk <= 8; msk <<= 1)
#pragma unroll
      for (int r = 0; r < 4; ++r) sm[r] += __shfl_xor(sm[r], msk);
#pragma unroll
    for (int r = 0; r < 4; ++r)
      Pl[(lg * 4 + r) * 40 + ln] = f2b(stv[r] / sm[r]);
#pragma unroll
    for (int r = 0; r < 4; ++r) Pl[ln * 40 + 16 + lg * 4 + r] = 0;
    short8 pa = *(const short8*)(Pl + ln * 40 + lg * 8);
#pragma unroll
    for (int nt4 = 0; nt4 < 4; ++nt4) {
      short8 vb = *(const short8*)(Vt + (nt4 * 16 + ln) * 40 + lg * 8);
      f32x4 acc = {0.f, 0.f, 0.f, 0.f};
      acc = __builtin_amdgcn_mfma_f32_16x16x32_bf16(pa, vb, acc, 0, 0, 0);
#pragma unroll
      for (int r = 0; r < 4; ++r) {
        int tq = lg * 4 + r;
        attn[((size_t)b * 3136 + (size_t)tq * 196 + p) * 768 + h * 64 + nt4 * 16 + ln] = f2b(acc[r]);
      }
    }
  }
}

// ---------- launch ----------
extern "C" void kernel_launch(void* const* d_in, const int* in_sizes, int n_in,
                              void* d_out, int out_size, void* d_ws, size_t ws_size,
                              hipStream_t stream) {
  const float* x  = (const float*)d_in[0];
  const float* Wq = (const float*)d_in[1];
  const float* bq = (const float*)d_in[2];
  const float* Wk = (const float*)d_in[3];
  const float* bk = (const float*)d_in[4];
  const float* Wv = (const float*)d_in[5];
  const float* bv = (const float*)d_in[6];
  const float* Wo = (const float*)d_in[7];
  const float* bo = (const float*)d_in[8];
  float* out = (float*)d_out;
  char* ws = (char*)d_ws;
  unsigned short* xb    = (unsigned short*)(ws + 0);          // 25088*768*2
  unsigned short* wqkvT = (unsigned short*)(ws + 38535168);   // 2304*768*2
  float*          bqkv  = (float*)(ws + 42074112);            // 2304*4
  unsigned short* woT   = (unsigned short*)(ws + 42083328);   // 768*768*2
  unsigned short* qkvb  = (unsigned short*)(ws + 43262976);   // 25088*2304*2
  unsigned short* attnb = (unsigned short*)(ws + 158868480);  // 25088*768*2

  k_prep<<<21120, 256, 0, stream>>>(x, xb, bq, bk, bv, bqkv, Wq, Wk, Wv, Wo, wqkvT, woT);
  k_gemm256<<<882, 512, 0, stream>>>(xb, wqkvT, bqkv, qkvb, 25088, 2304);
  k_attn_fused<<<3120, 256, 0, stream>>>(qkvb, attnb);
  k_gemm_out<<<dim3(4, 196), 256, 0, stream>>>(attnb, woT, bo, out, 25088, 768, 768);
}

// Round 11
// 244.106 us; speedup vs baseline: 1.0657x; 1.0018x over previous
//
#include <hip/hip_runtime.h>

// FactorizedDotProductAttention on MI355X (gfx950)
// B=8, N=3136 (=T16 * P196), C=768, H=12, hd=64. Heads 0-5: spatial attn over P=196
// per (b,t). Heads 6-11: temporal attn over T=16 per (b,p).
// Pipeline: prep (x->bf16 + W packs) ; QKV GEMM (256^2 8-phase, round-4 schedule,
// LDS-transpose coalesced epilogue) ; fused attn (round-7 known-good) ;
// out GEMM (128x192 dbuf, 784 blocks = 1 resident round at 3 blocks/CU).

typedef __attribute__((ext_vector_type(8))) short short8;
typedef __attribute__((ext_vector_type(4))) float f32x4;

typedef __attribute__((address_space(1))) void gvoid;
typedef __attribute__((address_space(3))) void lvoid;

__device__ __forceinline__ unsigned short f2b(float f) {
  unsigned int u = __float_as_uint(f);
  unsigned int r = (u + 0x7FFFu + ((u >> 16) & 1u)) >> 16;  // RNE
  return (unsigned short)r;
}

// ---------- kernel 1: prep = convert x (blocks 0..18815) + pack W (blocks 18816..21119) ----------
__global__ __launch_bounds__(256) void k_prep(
    const float* __restrict__ x, unsigned short* __restrict__ xb,
    const float* __restrict__ bq, const float* __restrict__ bk,
    const float* __restrict__ bv, float* __restrict__ bqkv,
    const float* __restrict__ Wq, const float* __restrict__ Wk,
    const float* __restrict__ Wv, const float* __restrict__ Wo,
    unsigned short* __restrict__ wqkvT, unsigned short* __restrict__ woT) {
  __shared__ float tile[32][33];
  if (blockIdx.x < 18816) {
    int tid = blockIdx.x * 256 + threadIdx.x;
    if (tid < 2304)
      bqkv[tid] = tid < 768 ? bq[tid] : (tid < 1536 ? bk[tid - 768] : bv[tid - 1536]);
    float4 v = ((const float4*)x)[tid];
    ushort4 o;
    o.x = f2b(v.x); o.y = f2b(v.y); o.z = f2b(v.z); o.w = f2b(v.w);
    ((ushort4*)xb)[tid] = o;
    return;
  }
  int bid = blockIdx.x - 18816;
  const float* W;
  unsigned short* dst;
  int n0, k0;
  if (bid < 1728) {
    int tn = bid % 72, tk = bid / 72;
    n0 = tn * 32; k0 = tk * 32;
    int which = n0 / 768;
    W = which == 0 ? Wq : (which == 1 ? Wk : Wv);
    dst = wqkvT;
  } else {
    int b2 = bid - 1728;
    int tn = b2 % 24, tk = b2 / 24;
    n0 = tn * 32; k0 = tk * 32;
    W = Wo; dst = woT;
  }
  int nn0 = n0 % 768;
  for (int i = threadIdx.x; i < 1024; i += 256) {
    int r = i >> 5, c = i & 31;
    tile[r][c] = W[(size_t)(k0 + r) * 768 + nn0 + c];
  }
  __syncthreads();
  for (int i = threadIdx.x; i < 1024; i += 256) {
    int r = i >> 5, c = i & 31;
    dst[(size_t)(n0 + r) * 768 + k0 + c] = f2b(tile[c][r]);
  }
}

// ================== 256x256 8-phase GEMM, K=768, 1 barrier/phase ==================
// Round-4 proven schedule (105.5us, MfmaUtil 36.4%). See prior rounds for audit.
// NEW: LDS-transpose epilogue — scalar 2B stores (4x32B transactions/instr, 1024
// wave-instrs, unhidden at 1 block/CU) replaced by LDS round-trip + 16 coalesced
// 16B stores/thread.

#define FENCE asm volatile("" ::: "memory")
#define BARRIER do { FENCE; __builtin_amdgcn_s_barrier(); FENCE; } while (0)
#define WAIT_LGKM0 asm volatile("s_waitcnt lgkmcnt(0)" ::: "memory")
#define WAIT_VM4 asm volatile("s_waitcnt vmcnt(4)" ::: "memory")

#define STAGE(PBASE, BUFBASE, HT, KT_) do {                                          \
    int kt__ = (KT_);                                                                \
    bool real__ = (kt__ < 12);                                                       \
    if (!real__) kt__ -= 12;                                                         \
    const unsigned short* src__ = (PBASE) + (HT) * 98304 + kt__ * 64;                \
    unsigned d0__ = real__ ? ((BUFBASE) + (HT) * 8192 + w * 512) : (65536u + w * 512); \
    unsigned d1__ = real__ ? ((BUFBASE) + (HT) * 8192 + 4096 + w * 512) : (65536u + w * 512); \
    __builtin_amdgcn_global_load_lds((const gvoid*)src__, (lvoid*)(lds + d0__), 16, 0, 0); \
    __builtin_amdgcn_global_load_lds((const gvoid*)(src__ + 49152), (lvoid*)(lds + d1__), 16, 0, 0); \
  } while (0)

#define LDA(MH, ABASE) do {                                                          \
    const unsigned short* ab__ = lds + (ABASE) + ((MH) * 128 + arow) * 64;           \
    _Pragma("unroll")                                                                \
    for (int mf = 0; mf < 4; ++mf) {                                                 \
      af[mf][0] = *(const short8*)(ab__ + mf * 1024 + s0);                           \
      af[mf][1] = *(const short8*)(ab__ + mf * 1024 + s1);                           \
    }                                                                                \
  } while (0)

#define LDB(NH, BBASE) do {                                                          \
    const unsigned short* bb__ = lds + (BBASE) + ((NH) * 128 + brow) * 64;           \
    _Pragma("unroll")                                                                \
    for (int nf = 0; nf < 2; ++nf) {                                                 \
      bf[nf][0] = *(const short8*)(bb__ + nf * 1024 + s0);                           \
      bf[nf][1] = *(const short8*)(bb__ + nf * 1024 + s1);                           \
    }                                                                                \
  } while (0)

#define MM(MH, NH) do {                                                              \
    __builtin_amdgcn_s_setprio(1);                                                   \
    _Pragma("unroll")                                                                \
    for (int mf = 0; mf < 4; ++mf) {                                                 \
      _Pragma("unroll")                                                              \
      for (int nf = 0; nf < 2; ++nf) {                                               \
        acc[MH][mf][NH][nf] = __builtin_amdgcn_mfma_f32_16x16x32_bf16(               \
            af[mf][0], bf[nf][0], acc[MH][mf][NH][nf], 0, 0, 0);                     \
        acc[MH][mf][NH][nf] = __builtin_amdgcn_mfma_f32_16x16x32_bf16(               \
            af[mf][1], bf[nf][1], acc[MH][mf][NH][nf], 0, 0, 0);                     \
      }                                                                              \
    }                                                                                \
    __builtin_amdgcn_s_setprio(0);                                                   \
  } while (0)

__global__ __launch_bounds__(512, 2) void k_gemm256(
    const unsigned short* __restrict__ A, const unsigned short* __restrict__ Bt,
    const float* __restrict__ bias, unsigned short* __restrict__ Cout,
    int M, int N) {
  __shared__ __align__(16) unsigned short lds[69632];
  const int nwg = gridDim.x;
  const int nbx = N >> 8;
  const int orig = blockIdx.x;
  const int q = nwg >> 3, r = nwg & 7;
  const int xcd = orig & 7, lin = orig >> 3;
  const int wg = (xcd < r ? xcd * (q + 1) : r * (q + 1) + (xcd - r) * q) + lin;
  const int m0 = (wg / nbx) << 8, n0 = (wg % nbx) << 8;

  const int tid = threadIdx.x;
  const int w = tid >> 6, l = tid & 63;
  const int wm = w >> 2, wn = w & 3;
  const int lg = l >> 4, ln = l & 15;
  const int arow = wm * 64 + ln;
  const int brow = wn * 32 + ln;
  const int s0 = (lg ^ (ln & 7)) * 8;
  const int s1 = s0 ^ 32;
  const int srow = tid >> 3;
  const int slg8 = ((tid & 7) ^ (srow & 7)) * 8;
  const unsigned short* pA = A + (size_t)(m0 + srow) * 768 + slg8;
  const unsigned short* pB = Bt + (size_t)(n0 + srow) * 768 + slg8;

  f32x4 acc[2][4][2][2] = {};

  STAGE(pA, 0,     0, 0);
  STAGE(pB, 16384, 0, 0);
  STAGE(pA, 0,     1, 0);
  STAGE(pB, 16384, 1, 0);
  STAGE(pA, 32768, 0, 1);
  STAGE(pB, 49152, 1, 1);
  WAIT_VM4;
  BARRIER;

  for (int it = 0; it < 6; ++it) {
    const int kt1 = 2 * it + 1, ktn0 = 2 * it + 2, ktn1 = 2 * it + 3;
    short8 af[4][2], bf[2][2];
    LDA(0, 0); LDB(0, 16384);
    STAGE(pA, 32768, 1, kt1);
    BARRIER; WAIT_LGKM0; MM(0, 0);
    LDB(1, 16384);
    STAGE(pB, 49152, 0, kt1);
    BARRIER; WAIT_LGKM0; MM(0, 1);
    LDA(1, 0);
    STAGE(pA, 0, 0, ktn0);
    BARRIER; WAIT_LGKM0; MM(1, 1);
    LDB(0, 16384);
    STAGE(pB, 16384, 1, ktn0);
    WAIT_VM4;
    BARRIER; WAIT_LGKM0; MM(1, 0);
    LDA(0, 32768); LDB(0, 49152);
    STAGE(pA, 0, 1, ktn0);
    BARRIER; WAIT_LGKM0; MM(0, 0);
    LDB(1, 49152);
    STAGE(pB, 16384, 0, ktn0);
    BARRIER; WAIT_LGKM0; MM(0, 1);
    LDA(1, 32768);
    STAGE(pA, 32768, 0, ktn1);
    BARRIER; WAIT_LGKM0; MM(1, 1);
    LDB(0, 49152);
    STAGE(pB, 49152, 1, ktn1);
    WAIT_VM4;
    BARRIER; WAIT_LGKM0; MM(1, 0);
  }

  // ---- LDS-transpose epilogue ----
  // All waves have completed their own lgkm0 (last phase) before this barrier,
  // so every ds_read of the main loop is retired before any epilogue write.
  asm volatile("s_waitcnt vmcnt(0)" ::: "memory");  // all staging writes retired too
  BARRIER;
#pragma unroll
  for (int mh = 0; mh < 2; ++mh)
#pragma unroll
    for (int mf = 0; mf < 4; ++mf) {
      const int row = mh * 128 + wm * 64 + mf * 16 + lg * 4;
#pragma unroll
      for (int nh = 0; nh < 2; ++nh)
#pragma unroll
        for (int nf = 0; nf < 2; ++nf) {
          const int col = nh * 128 + wn * 32 + nf * 16 + ln;
          const float bval = bias[n0 + col];
#pragma unroll
          for (int rr = 0; rr < 4; ++rr)
            lds[(row + rr) * 256 + col] = f2b(acc[mh][mf][nh][nf][rr] + bval);
        }
    }
  WAIT_LGKM0;  // own writes done
  BARRIER;     // everyone's writes done
#pragma unroll
  for (int i = 0; i < 16; ++i) {
    const int s = i * 512 + tid;                 // short8 slot in [256][256] bf16 tile
    const int row = s >> 5, col = (s & 31) * 8;  // 32 slots per row
    short8 v = *(const short8*)(lds + s * 8);
    *(short8*)(Cout + (size_t)(m0 + row) * N + n0 + col) = v;
  }
}

// ---------- out GEMM: 128x192 tile, BK=32, double-buffered ----------
// Grid = 196 x 4 = 784 blocks; at 3 blocks/CU (LDS 44KB, launch_bounds(256,3))
// 768 are co-resident -> ~1 dispatch round. 4 waves (2m x 2n), wave tile 64x96.
__global__ __launch_bounds__(256, 3) void k_gemm_out(
    const unsigned short* __restrict__ A, const unsigned short* __restrict__ Bt,
    const float* __restrict__ bias, float* __restrict__ C,
    int M, int N, int K) {
  __shared__ __align__(16) unsigned short lds[22528];  // 2 x (A 4096 + B 6144) + 2048 dummy
  const int tid = threadIdx.x;
  const int w = tid >> 6, l = tid & 63;
  const int lg = l >> 4, ln = l & 15;
  const int m0 = blockIdx.y * 128, n0 = blockIdx.x * 192;
  const int wr = (w >> 1) * 64, wc = (w & 1) * 96;
  f32x4 acc[4][6] = {};
  const int srow = tid >> 2;
  const int sg = ((tid & 3) ^ (srow & 3)) * 8;
  const unsigned short* ga = A + (size_t)(m0 + srow) * K + sg;
  const unsigned short* gb = Bt + (size_t)(n0 + srow) * K + sg;
  const int wofs = w * 512;
  const int rs = (lg ^ (ln & 3)) * 8;

#define OSTAGE(BUF, K0) do {                                                                       \
    const unsigned base__ = (unsigned)(BUF) * 10240u;                                              \
    _Pragma("unroll")                                                                              \
    for (int j = 0; j < 2; ++j)                                                                    \
      __builtin_amdgcn_global_load_lds((const gvoid*)(ga + (size_t)(j * 64) * K + (K0)),           \
                                       (lvoid*)(lds + base__ + j * 2048 + wofs), 16, 0, 0);        \
    _Pragma("unroll")                                                                              \
    for (int j = 0; j < 3; ++j)                                                                    \
      __builtin_amdgcn_global_load_lds((const gvoid*)(gb + (size_t)(j * 64) * K + (K0)),           \
                                       (lvoid*)(lds + base__ + 4096 + j * 2048 + wofs), 16, 0, 0); \
  } while (0)

  OSTAGE(0, 0);
  asm volatile("s_waitcnt vmcnt(0)" ::: "memory");
  BARRIER;
  const int nk = K >> 5;  // 24
  for (int i = 0; i < nk; ++i) {
    if (i + 1 < nk) OSTAGE((i + 1) & 1, (i + 1) * 32);
    const unsigned short* as = lds + (i & 1) * 10240;
    const unsigned short* bs = as + 4096;
    short8 a[4], b[6];
#pragma unroll
    for (int mt = 0; mt < 4; ++mt)
      a[mt] = *(const short8*)(as + (wr + mt * 16 + ln) * 32 + rs);
#pragma unroll
    for (int nt = 0; nt < 6; ++nt)
      b[nt] = *(const short8*)(bs + (wc + nt * 16 + ln) * 32 + rs);
#pragma unroll
    for (int mt = 0; mt < 4; ++mt)
#pragma unroll
      for (int nt = 0; nt < 6; ++nt)
        acc[mt][nt] = __builtin_amdgcn_mfma_f32_16x16x32_bf16(a[mt], b[nt], acc[mt][nt], 0, 0, 0);
    asm volatile("s_waitcnt vmcnt(0)" ::: "memory");
    BARRIER;
  }
#pragma unroll
  for (int nt = 0; nt < 6; ++nt) {
    int col = n0 + wc + nt * 16 + ln;
    float bval = bias[col];
#pragma unroll
    for (int mt = 0; mt < 4; ++mt) {
      int row = m0 + wr + mt * 16 + lg * 4;
#pragma unroll
      for (int r = 0; r < 4; ++r)
        C[(size_t)(row + r) * N + col] = acc[mt][nt][r] + bval;
    }
  }
#undef OSTAGE
}

// ---------- fused attention (round-7 known-good) ----------
__global__ __launch_bounds__(256) void k_attn_fused(
    const unsigned short* __restrict__ qkv, unsigned short* __restrict__ attn) {
  __shared__ __align__(16) unsigned short smem[29696];  // 59392 B
  const int w = threadIdx.x >> 6, l = threadIdx.x & 63;
  const int lg = l >> 4, ln = l & 15;
  const float scale = 0.125f;
  if (blockIdx.x < 768) {
    // ---- spatial: heads 0-5 ----
    const int bi = blockIdx.x;
    const int h = bi % 6;
    const int t = (bi / 6) % 16;
    const int b = bi / 96;
    const int base_row = b * 3136 + t * 196;
    unsigned short* Vt = smem;           // [64][232]
    unsigned short* Pl = smem + 14848;   // [4][16][232]
    for (int i = threadIdx.x; i < 196 * 8; i += 256) {
      int key = i >> 3, d0 = (i & 7) * 8;
      short8 v = *(const short8*)(qkv + (size_t)(base_row + key) * 2304 + 1536 + h * 64 + d0);
#pragma unroll
      for (int j = 0; j < 8; ++j) Vt[(d0 + j) * 232 + key] = (unsigned short)v[j];
    }
    for (int i = threadIdx.x; i < 64 * 28; i += 256)
      Vt[(i / 28) * 232 + 196 + (i % 28)] = 0;
    __syncthreads();
    for (int mt = w; mt < 13; mt += 4) {
      int qm = mt * 16 + ln; if (qm > 195) qm = 195;
      const size_t qoff = (size_t)(base_row + qm) * 2304 + h * 64 + lg * 8;
      short8 qa0 = *(const short8*)(qkv + qoff);
      short8 qa1 = *(const short8*)(qkv + qoff + 32);
      f32x4 st[13];
#pragma unroll
      for (int nt = 0; nt < 13; ++nt) {
        int kn = nt * 16 + ln; if (kn > 195) kn = 195;
        const size_t koff = (size_t)(base_row + kn) * 2304 + 768 + h * 64 + lg * 8;
        short8 kb0 = *(const short8*)(qkv + koff);
        short8 kb1 = *(const short8*)(qkv + koff + 32);
        f32x4 s = {0.f, 0.f, 0.f, 0.f};
        s = __builtin_amdgcn_mfma_f32_16x16x32_bf16(qa0, kb0, s, 0, 0, 0);
        s = __builtin_amdgcn_mfma_f32_16x16x32_bf16(qa1, kb1, s, 0, 0, 0);
        st[nt] = s;
      }
      float mr[4] = {-1e30f, -1e30f, -1e30f, -1e30f};
#pragma unroll
      for (int nt = 0; nt < 13; ++nt) {
        bool valid = (nt * 16 + ln) < 196;
#pragma unroll
        for (int r = 0; r < 4; ++r) {
          float v = valid ? st[nt][r] * scale : -1e30f;
          st[nt][r] = v;
          mr[r] = fmaxf(mr[r], v);
        }
      }
#pragma unroll
      for (int msk = 1; msk <= 8; msk <<= 1)
#pragma unroll
        for (int r = 0; r < 4; ++r) mr[r] = fmaxf(mr[r], __shfl_xor(mr[r], msk));
      float sm[4] = {0.f, 0.f, 0.f, 0.f};
#pragma unroll
      for (int nt = 0; nt < 13; ++nt)
#pragma unroll
        for (int r = 0; r < 4; ++r) {
          float p = __expf(st[nt][r] - mr[r]);
          st[nt][r] = p;
          sm[r] += p;
        }
#pragma unroll
      for (int msk = 1; msk <= 8; msk <<= 1)
#pragma unroll
        for (int r = 0; r < 4; ++r) sm[r] += __shfl_xor(sm[r], msk);
      float inv[4];
#pragma unroll
      for (int r = 0; r < 4; ++r) inv[r] = 1.f / sm[r];
      unsigned short* Pw = Pl + w * 16 * 232;
#pragma unroll
      for (int nt = 0; nt < 13; ++nt)
#pragma unroll
        for (int r = 0; r < 4; ++r)
          Pw[(lg * 4 + r) * 232 + nt * 16 + ln] = f2b(st[nt][r] * inv[r]);
#pragma unroll
      for (int r = 0; r < 4; ++r) Pw[ln * 232 + 208 + lg * 4 + r] = 0;
#pragma unroll
      for (int nt4 = 0; nt4 < 4; ++nt4) {
        f32x4 acc = {0.f, 0.f, 0.f, 0.f};
#pragma unroll
        for (int ks = 0; ks < 7; ++ks) {
          short8 pa = *(const short8*)(Pw + ln * 232 + ks * 32 + lg * 8);
          short8 vb = *(const short8*)(Vt + (nt4 * 16 + ln) * 232 + ks * 32 + lg * 8);
          acc = __builtin_amdgcn_mfma_f32_16x16x32_bf16(pa, vb, acc, 0, 0, 0);
        }
#pragma unroll
        for (int r = 0; r < 4; ++r) {
          int m = mt * 16 + lg * 4 + r;
          if (m < 196)
            attn[(size_t)(base_row + m) * 768 + h * 64 + nt4 * 16 + ln] = f2b(acc[r]);
        }
      }
    }
  } else {
    // ---- temporal: heads 6-11, one wave per (b,p,h) ----
    const int u = (blockIdx.x - 768) * 4 + w;  // 9408 = 8*196*6
    const int b = u / 1176;
    const int rem = u % 1176;
    const int p = rem / 6;
    const int h = 6 + rem % 6;
    const size_t rowb = (size_t)b * 3136 + p;
    unsigned short* Vt = smem + w * 2560;          // [64][40]
    unsigned short* Pl = smem + 10240 + w * 640;   // [16][40]
    for (int i = l; i < 128; i += 64) {
      int tt = i >> 3, d0 = (i & 7) * 8;
      short8 v = *(const short8*)(qkv + (rowb + (size_t)tt * 196) * 2304 + 1536 + h * 64 + d0);
#pragma unroll
      for (int j = 0; j < 8; ++j) Vt[(d0 + j) * 40 + tt] = (unsigned short)v[j];
    }
    for (int i = l; i < 1024; i += 64)
      Vt[(i >> 4) * 40 + 16 + (i & 15)] = 0;
    const size_t qoff = (rowb + (size_t)ln * 196) * 2304 + h * 64 + lg * 8;
    short8 qa0 = *(const short8*)(qkv + qoff);
    short8 qa1 = *(const short8*)(qkv + qoff + 32);
    short8 kb0 = *(const short8*)(qkv + qoff + 768);
    short8 kb1 = *(const short8*)(qkv + qoff + 768 + 32);
    f32x4 s = {0.f, 0.f, 0.f, 0.f};
    s = __builtin_amdgcn_mfma_f32_16x16x32_bf16(qa0, kb0, s, 0, 0, 0);
    s = __builtin_amdgcn_mfma_f32_16x16x32_bf16(qa1, kb1, s, 0, 0, 0);
    float stv[4], mr[4];
#pragma unroll
    for (int r = 0; r < 4; ++r) { stv[r] = s[r] * scale; mr[r] = stv[r]; }
#pragma unroll
    for (int msk = 1; msk <= 8; msk <<= 1)
#pragma unroll
      for (int r = 0; r < 4; ++r) mr[r] = fmaxf(mr[r], __shfl_xor(mr[r], msk));
    float sm[4];
#pragma unroll
    for (int r = 0; r < 4; ++r) { stv[r] = __expf(stv[r] - mr[r]); sm[r] = stv[r]; }
#pragma unroll
    for (int msk = 1; msk <= 8; msk <<= 1)
#pragma unroll
      for (int r = 0; r < 4; ++r) sm[r] += __shfl_xor(sm[r], msk);
#pragma unroll
    for (int r = 0; r < 4; ++r)
      Pl[(lg * 4 + r) * 40 + ln] = f2b(stv[r] / sm[r]);
#pragma unroll
    for (int r = 0; r < 4; ++r) Pl[ln * 40 + 16 + lg * 4 + r] = 0;
    short8 pa = *(const short8*)(Pl + ln * 40 + lg * 8);
#pragma unroll
    for (int nt4 = 0; nt4 < 4; ++nt4) {
      short8 vb = *(const short8*)(Vt + (nt4 * 16 + ln) * 40 + lg * 8);
      f32x4 acc = {0.f, 0.f, 0.f, 0.f};
      acc = __builtin_amdgcn_mfma_f32_16x16x32_bf16(pa, vb, acc, 0, 0, 0);
#pragma unroll
      for (int r = 0; r < 4; ++r) {
        int tq = lg * 4 + r;
        attn[((size_t)b * 3136 + (size_t)tq * 196 + p) * 768 + h * 64 + nt4 * 16 + ln] = f2b(acc[r]);
      }
    }
  }
}

// ---------- launch ----------
extern "C" void kernel_launch(void* const* d_in, const int* in_sizes, int n_in,
                              void* d_out, int out_size, void* d_ws, size_t ws_size,
                              hipStream_t stream) {
  const float* x  = (const float*)d_in[0];
  const float* Wq = (const float*)d_in[1];
  const float* bq = (const float*)d_in[2];
  const float* Wk = (const float*)d_in[3];
  const float* bk = (const float*)d_in[4];
  const float* Wv = (const float*)d_in[5];
  const float* bv = (const float*)d_in[6];
  const float* Wo = (const float*)d_in[7];
  const float* bo = (const float*)d_in[8];
  float* out = (float*)d_out;
  char* ws = (char*)d_ws;
  unsigned short* xb    = (unsigned short*)(ws + 0);          // 25088*768*2
  unsigned short* wqkvT = (unsigned short*)(ws + 38535168);   // 2304*768*2
  float*          bqkv  = (float*)(ws + 42074112);            // 2304*4
  unsigned short* woT   = (unsigned short*)(ws + 42083328);   // 768*768*2
  unsigned short* qkvb  = (unsigned short*)(ws + 43262976);   // 25088*2304*2
  unsigned short* attnb = (unsigned short*)(ws + 158868480);  // 25088*768*2

  k_prep<<<21120, 256, 0, stream>>>(x, xb, bq, bk, bv, bqkv, Wq, Wk, Wv, Wo, wqkvT, woT);
  k_gemm256<<<882, 512, 0, stream>>>(xb, wqkvT, bqkv, qkvb, 25088, 2304);
  k_attn_fused<<<3120, 256, 0, stream>>>(qkvb, attnb);
  k_gemm_out<<<dim3(4, 196), 256, 0, stream>>>(attnb, woT, bo, out, 25088, 768, 768);
}